// Round 1
// baseline (1574.443 us; speedup 1.0000x reference)
//
#include <hip/hip_runtime.h>
#include <hip/hip_bf16.h>

#define B_ 2
#define S_ 4096
#define D_ 768
#define H_ 12
#define DH_ 64
#define W_ 256
#define G_ 8
#define NEG_ (-1e9f)

// ---------------------------------------------------------------------------
// Kernel 1: projection GEMM.  X:(B*S, D) row-major @ Wm:(D, D) row-major.
// Output written directly in head layout: out[((b*H + h)*S + s)*DH + d],
// where GEMM row m = b*S + s and GEMM col n = h*DH + d.  BN == DH == 64 so
// each block's column tile lies within one head.
// ---------------------------------------------------------------------------
#define BM_ 64
#define BN_ 64
#define BK_ 16

__global__ __launch_bounds__(256) void proj_gemm(const float* __restrict__ X,
                                                 const float* __restrict__ Wm,
                                                 float* __restrict__ out,
                                                 float scale) {
    __shared__ float As[BK_][BM_ + 4];  // transposed A tile: As[k][m]
    __shared__ float Bs[BK_][BN_ + 4];  // Bs[k][n]

    const int tid = threadIdx.x;
    const int m0 = blockIdx.x * BM_;
    const int n0 = blockIdx.y * BN_;

    const int tx = tid & 15;   // N direction, 4 cols each
    const int ty = tid >> 4;   // M direction, 4 rows each

    const int la_m = tid >> 2;          // 0..63
    const int la_k = (tid & 3) * 4;     // 0,4,8,12
    const int lb_k = tid >> 4;          // 0..15
    const int lb_n = (tid & 15) * 4;    // 0..60

    float acc[4][4] = {};

    for (int k0 = 0; k0 < D_; k0 += BK_) {
        const float4 av = *(const float4*)&X[(size_t)(m0 + la_m) * D_ + k0 + la_k];
        const float4 bv = *(const float4*)&Wm[(size_t)(k0 + lb_k) * D_ + n0 + lb_n];
        As[la_k + 0][la_m] = av.x;
        As[la_k + 1][la_m] = av.y;
        As[la_k + 2][la_m] = av.z;
        As[la_k + 3][la_m] = av.w;
        *(float4*)&Bs[lb_k][lb_n] = bv;
        __syncthreads();

#pragma unroll
        for (int kk = 0; kk < BK_; ++kk) {
            float a0 = As[kk][ty * 4 + 0];
            float a1 = As[kk][ty * 4 + 1];
            float a2 = As[kk][ty * 4 + 2];
            float a3 = As[kk][ty * 4 + 3];
            float b0 = Bs[kk][tx * 4 + 0];
            float b1 = Bs[kk][tx * 4 + 1];
            float b2 = Bs[kk][tx * 4 + 2];
            float b3 = Bs[kk][tx * 4 + 3];
            acc[0][0] += a0 * b0; acc[0][1] += a0 * b1; acc[0][2] += a0 * b2; acc[0][3] += a0 * b3;
            acc[1][0] += a1 * b0; acc[1][1] += a1 * b1; acc[1][2] += a1 * b2; acc[1][3] += a1 * b3;
            acc[2][0] += a2 * b0; acc[2][1] += a2 * b1; acc[2][2] += a2 * b2; acc[2][3] += a2 * b3;
            acc[3][0] += a3 * b0; acc[3][1] += a3 * b1; acc[3][2] += a3 * b2; acc[3][3] += a3 * b3;
        }
        __syncthreads();
    }

    // Epilogue: out col n = n0 + tx*4 + j, head hh = n0/64 (constant per block).
    const int hh = n0 / DH_;
    const int dcol = tx * 4;
#pragma unroll
    for (int i = 0; i < 4; ++i) {
        const int m = m0 + ty * 4 + i;
        const int b = m / S_;
        const int s = m - b * S_;
        float4 r;
        r.x = acc[i][0] * scale;
        r.y = acc[i][1] * scale;
        r.z = acc[i][2] * scale;
        r.w = acc[i][3] * scale;
        *(float4*)&out[((size_t)(b * H_ + hh) * S_ + s) * DH_ + dcol] = r;
    }
}

// ---------------------------------------------------------------------------
// Kernel 1b: qg GEMM — only the first G sequence positions are needed.
// qg[(b*G+g)*D + c] = scale * sum_k X[(b*S+g)*D + k] * Wm[k*D + c]
// ---------------------------------------------------------------------------
__global__ __launch_bounds__(256) void qg_gemm(const float* __restrict__ X,
                                               const float* __restrict__ Wm,
                                               float* __restrict__ qg,
                                               float scale) {
    __shared__ float xr[D_];
    const int row = blockIdx.x;           // 0..B*G-1
    const int b = row / G_;
    const int g = row - b * G_;
    for (int i = threadIdx.x; i < D_; i += 256)
        xr[i] = X[((size_t)b * S_ + g) * D_ + i];
    __syncthreads();
    for (int c = threadIdx.x; c < D_; c += 256) {
        float acc = 0.f;
        for (int kk = 0; kk < D_; ++kk) acc += xr[kk] * Wm[(size_t)kk * D_ + c];
        qg[(size_t)row * D_ + c] = acc * scale;
    }
}

// ---------------------------------------------------------------------------
// Kernel 2: windowed attention, flash-style online softmax.
// One block per (b, h, chunk n); one thread per query (W=256 threads).
// Keys: G global keys (k[b,h,0..G-1]) always valid + window keys
// p in [qp-W, qp+W] with p in [G, S) and attention_mask[p] > 0.5.
// ---------------------------------------------------------------------------
__global__ __launch_bounds__(256) void win_attn(const float* __restrict__ q,
                                                const float* __restrict__ k,
                                                const float* __restrict__ v,
                                                const float* __restrict__ am,
                                                float* __restrict__ out) {
    const int n = blockIdx.x;
    const int h = blockIdx.y;
    const int b = blockIdx.z;
    const int tid = threadIdx.x;
    const int qp = n * W_ + tid;

    const float* __restrict__ kbase = &k[(size_t)(b * H_ + h) * S_ * DH_];
    const float* __restrict__ vbase = &v[(size_t)(b * H_ + h) * S_ * DH_];

    // Query row into registers.
    float qreg[DH_];
    {
        const float* qrow = &q[((size_t)(b * H_ + h) * S_ + qp) * DH_];
#pragma unroll
        for (int d = 0; d < DH_; d += 4) {
            float4 t = *(const float4*)&qrow[d];
            qreg[d] = t.x; qreg[d + 1] = t.y; qreg[d + 2] = t.z; qreg[d + 3] = t.w;
        }
    }

    __shared__ float kt[64 * DH_];
    __shared__ float vt[64 * DH_];
    __shared__ float gk[G_ * DH_];
    __shared__ float gv[G_ * DH_];
    __shared__ float amt[64];

    // Stage global keys/values (rows 0..G-1).
    for (int i = tid; i < G_ * DH_; i += 256) {
        gk[i] = kbase[i];
        gv[i] = vbase[i];
    }
    __syncthreads();

    float m = -1e30f, l = 0.f;
    float o[DH_];
#pragma unroll
    for (int d = 0; d < DH_; ++d) o[d] = 0.f;

    // --- G global keys (never masked in the reference) ---
#pragma unroll
    for (int g = 0; g < G_; ++g) {
        float s = 0.f;
#pragma unroll
        for (int d = 0; d < DH_; ++d) s += qreg[d] * gk[g * DH_ + d];
        if (s > m) {
            const float c = __expf(m - s);
            l *= c;
#pragma unroll
            for (int d = 0; d < DH_; ++d) o[d] *= c;
            m = s;
        }
        const float p = __expf(s - m);
        l += p;
#pragma unroll
        for (int d = 0; d < DH_; ++d) o[d] += p * gv[g * DH_ + d];
    }

    // --- window keys: 3W range [n*W - W, n*W + 2W), tiles of 64 ---
    const int pbase = n * W_ - W_;
    for (int t0 = 0; t0 < 3 * W_; t0 += 64) {
        __syncthreads();  // protect LDS reuse
        for (int i4 = tid; i4 < 64 * DH_ / 4; i4 += 256) {
            const int r = i4 >> 4;          // 16 float4 per row
            const int p = pbase + t0 + r;
            float4 kv = make_float4(0.f, 0.f, 0.f, 0.f);
            float4 vv = make_float4(0.f, 0.f, 0.f, 0.f);
            if (p >= 0 && p < S_) {
                kv = *(const float4*)&kbase[(size_t)p * DH_ + (i4 & 15) * 4];
                vv = *(const float4*)&vbase[(size_t)p * DH_ + (i4 & 15) * 4];
            }
            *(float4*)&kt[i4 * 4] = kv;
            *(float4*)&vt[i4 * 4] = vv;
        }
        if (tid < 64) {
            const int p = pbase + t0 + tid;
            amt[tid] = (p >= 0 && p < S_) ? am[(size_t)b * S_ + p] : 0.f;
        }
        __syncthreads();

        for (int j = 0; j < 64; ++j) {
            const int p = pbase + t0 + j;
            const bool valid = (p >= G_) && (p < S_) && (p >= qp - W_) &&
                               (p <= qp + W_) && (amt[j] > 0.5f);
            if (!valid) continue;
            float s = 0.f;
#pragma unroll
            for (int d = 0; d < DH_; ++d) s += qreg[d] * kt[j * DH_ + d];
            if (s > m) {
                const float c = __expf(m - s);
                l *= c;
#pragma unroll
                for (int d = 0; d < DH_; ++d) o[d] *= c;
                m = s;
            }
            const float p_ = __expf(s - m);
            l += p_;
#pragma unroll
            for (int d = 0; d < DH_; ++d) o[d] += p_ * vt[j * DH_ + d];
        }
    }

    // Final normalize + write in (B, S, H*DH) layout.
    const float inv = 1.0f / l;
    float* orow = &out[((size_t)b * S_ + qp) * D_ + h * DH_];
#pragma unroll
    for (int d = 0; d < DH_; d += 4) {
        float4 r;
        r.x = o[d] * inv; r.y = o[d + 1] * inv; r.z = o[d + 2] * inv; r.w = o[d + 3] * inv;
        *(float4*)&orow[d] = r;
    }
}

// ---------------------------------------------------------------------------
// Kernel 3: global attention for the first G rows. One block per (b,h,g).
// Two-pass softmax over all S keys of kg, then prob @ vg. Overwrites the
// first G output rows (launched after win_attn on the same stream).
// ---------------------------------------------------------------------------
__global__ __launch_bounds__(256) void glob_attn(const float* __restrict__ qg,
                                                 const float* __restrict__ kg,
                                                 const float* __restrict__ vg,
                                                 const float* __restrict__ am,
                                                 float* __restrict__ out) {
    const int g = blockIdx.x;
    const int h = blockIdx.y;
    const int b = blockIdx.z;
    const int tid = threadIdx.x;

    __shared__ float sc[S_];      // 16 KB
    __shared__ float qs[DH_];
    __shared__ float red[256];
    __shared__ float red2[4][DH_];

    if (tid < DH_) qs[tid] = qg[(size_t)(b * G_ + g) * D_ + h * DH_ + tid];
    __syncthreads();

    const float* __restrict__ kgb = &kg[(size_t)(b * H_ + h) * S_ * DH_];
    const float* __restrict__ vgb = &vg[(size_t)(b * H_ + h) * S_ * DH_];

    float lmax = -1e30f;
    for (int s = tid; s < S_; s += 256) {
        float acc = 0.f;
#pragma unroll
        for (int d = 0; d < DH_; d += 4) {
            float4 kv = *(const float4*)&kgb[(size_t)s * DH_ + d];
            acc += qs[d] * kv.x + qs[d + 1] * kv.y + qs[d + 2] * kv.z + qs[d + 3] * kv.w;
        }
        if (!(am[(size_t)b * S_ + s] > 0.5f)) acc = NEG_;
        sc[s] = acc;
        lmax = fmaxf(lmax, acc);
    }
    red[tid] = lmax;
    __syncthreads();
    for (int off = 128; off > 0; off >>= 1) {
        if (tid < off) red[tid] = fmaxf(red[tid], red[tid + off]);
        __syncthreads();
    }
    const float mx = red[0];
    __syncthreads();

    float lsum = 0.f;
    for (int s = tid; s < S_; s += 256) {
        const float e = __expf(sc[s] - mx);
        sc[s] = e;
        lsum += e;
    }
    red[tid] = lsum;
    __syncthreads();
    for (int off = 128; off > 0; off >>= 1) {
        if (tid < off) red[tid] += red[tid + off];
        __syncthreads();
    }
    const float l = red[0];
    __syncthreads();

    // Phase 2: out[d] = sum_s p_s * vg[s][d]
    const int d = tid & 63;
    const int grp = tid >> 6;  // 0..3
    float acc = 0.f;
    for (int s = grp; s < S_; s += 4) acc += sc[s] * vgb[(size_t)s * DH_ + d];
    red2[grp][d] = acc;
    __syncthreads();
    if (tid < DH_) {
        const float r = (red2[0][tid] + red2[1][tid] + red2[2][tid] + red2[3][tid]) / l;
        out[((size_t)b * S_ + g) * D_ + h * DH_ + tid] = r;
    }
}

// ---------------------------------------------------------------------------
extern "C" void kernel_launch(void* const* d_in, const int* in_sizes, int n_in,
                              void* d_out, int out_size, void* d_ws, size_t ws_size,
                              hipStream_t stream) {
    (void)in_sizes; (void)n_in; (void)out_size; (void)ws_size;

    const float* hs    = (const float*)d_in[0];
    const float* amask = (const float*)d_in[1];
    const float* Wq    = (const float*)d_in[2];
    const float* Wk    = (const float*)d_in[3];
    const float* Wv    = (const float*)d_in[4];
    const float* Wqg   = (const float*)d_in[5];
    const float* Wkg   = (const float*)d_in[6];
    const float* Wvg   = (const float*)d_in[7];
    float* out = (float*)d_out;
    float* ws  = (float*)d_ws;

    const size_t per = (size_t)B_ * H_ * S_ * DH_;  // 6,291,456 floats
    float* q  = ws;
    float* k  = q + per;
    float* v  = k + per;
    float* kg = v + per;
    float* vg = kg + per;
    float* qg = vg + per;  // B*G*D floats

    const float scale = 0.125f;  // 1/sqrt(64)

    dim3 gg(B_ * S_ / BM_, D_ / BN_);  // (128, 12)
    proj_gemm<<<gg, 256, 0, stream>>>(hs, Wq,  q,  scale);
    proj_gemm<<<gg, 256, 0, stream>>>(hs, Wk,  k,  1.0f);
    proj_gemm<<<gg, 256, 0, stream>>>(hs, Wv,  v,  1.0f);
    proj_gemm<<<gg, 256, 0, stream>>>(hs, Wkg, kg, 1.0f);
    proj_gemm<<<gg, 256, 0, stream>>>(hs, Wvg, vg, 1.0f);

    qg_gemm<<<B_ * G_, 256, 0, stream>>>(hs, Wqg, qg, scale);

    win_attn<<<dim3(S_ / W_, H_, B_), 256, 0, stream>>>(q, k, v, amask, out);
    glob_attn<<<dim3(G_, H_, B_), 256, 0, stream>>>(qg, kg, vg, amask, out);
}

// Round 2
// 601.275 us; speedup vs baseline: 2.6185x; 2.6185x over previous
//
#include <hip/hip_runtime.h>

#define B_ 2
#define S_ 4096
#define D_ 768
#define H_ 12
#define DH_ 64
#define W_ 256
#define G_ 8
#define NEG_ (-1e9f)

typedef __attribute__((ext_vector_type(4))) float f32x4;
typedef __attribute__((ext_vector_type(8))) short s16x8;
typedef __attribute__((ext_vector_type(4))) short s16x4;
typedef unsigned short ushort_t;

__device__ __forceinline__ unsigned short f2bf(float f) {
    union { float f; unsigned u; } v; v.f = f;
    unsigned r = v.u + 0x7FFFu + ((v.u >> 16) & 1u);
    return (unsigned short)(r >> 16);
}
__device__ __forceinline__ float bf2f(unsigned short b) {
    union { unsigned u; float f; } v; v.u = ((unsigned)b) << 16;
    return v.f;
}

// ---------------------------------------------------------------------------
// hs fp32 -> bf16
// ---------------------------------------------------------------------------
__global__ __launch_bounds__(256) void convert_hs(const float* __restrict__ x,
                                                  ushort_t* __restrict__ y, int n8) {
    int i = blockIdx.x * 256 + threadIdx.x;
    if (i >= n8) return;
    float4 a = *(const float4*)&x[(size_t)i * 8];
    float4 c = *(const float4*)&x[(size_t)i * 8 + 4];
    s16x8 o;
    o[0] = (short)f2bf(a.x); o[1] = (short)f2bf(a.y);
    o[2] = (short)f2bf(a.z); o[3] = (short)f2bf(a.w);
    o[4] = (short)f2bf(c.x); o[5] = (short)f2bf(c.y);
    o[6] = (short)f2bf(c.z); o[7] = (short)f2bf(c.w);
    *(s16x8*)&y[(size_t)i * 8] = o;
}

// ---------------------------------------------------------------------------
// Weights: transpose+convert into Wt[w*768 + n][k] = W_w[k][n] (bf16).
// Scale 0.125 folded into Wq (w==0).  Grid (24,24,5), 32x32 tiles.
// ---------------------------------------------------------------------------
__global__ __launch_bounds__(256) void convert_wt(const float* __restrict__ W0,
                                                  const float* __restrict__ W1,
                                                  const float* __restrict__ W2,
                                                  const float* __restrict__ W3,
                                                  const float* __restrict__ W4,
                                                  ushort_t* __restrict__ wt) {
    __shared__ float tile[32][33];
    const int w = blockIdx.z;
    const float* Wsrc = (w == 0) ? W0 : (w == 1) ? W1 : (w == 2) ? W2 : (w == 3) ? W3 : W4;
    const float scl = (w == 0) ? 0.125f : 1.0f;
    const int k0 = blockIdx.x * 32;
    const int n0 = blockIdx.y * 32;
    const int t = threadIdx.x;
    const int r = t >> 3, c4 = (t & 7) * 4;
    float4 src = *(const float4*)&Wsrc[(size_t)(k0 + r) * D_ + n0 + c4];
    tile[r][c4 + 0] = src.x; tile[r][c4 + 1] = src.y;
    tile[r][c4 + 2] = src.z; tile[r][c4 + 3] = src.w;
    __syncthreads();
    s16x4 o;
    o[0] = (short)f2bf(tile[c4 + 0][r] * scl);
    o[1] = (short)f2bf(tile[c4 + 1][r] * scl);
    o[2] = (short)f2bf(tile[c4 + 2][r] * scl);
    o[3] = (short)f2bf(tile[c4 + 3][r] * scl);
    *(s16x4*)&wt[((size_t)(w * D_ + n0 + r)) * D_ + k0 + c4] = o;
}

// ---------------------------------------------------------------------------
// Fused projection GEMM: A = hs_bf [8192][768], Bt = wt [3840][768] (n-major).
// 128x128 tile, 4 waves (2x2), BK=32, mfma_f32_16x16x32_bf16.
// Epilogue -> bf16 head layout [b,h,s,d] into per-projection buffers.
// ---------------------------------------------------------------------------
#define PLDA 40

__global__ __launch_bounds__(256, 2) void proj_mfma(const ushort_t* __restrict__ A,
                                                    const ushort_t* __restrict__ Bt,
                                                    ushort_t* __restrict__ oq,
                                                    ushort_t* __restrict__ ok,
                                                    ushort_t* __restrict__ ov,
                                                    ushort_t* __restrict__ okg,
                                                    ushort_t* __restrict__ ovg) {
    __shared__ ushort_t Al[128 * PLDA];
    __shared__ ushort_t Bl[128 * PLDA];
    const int t = threadIdx.x;
    const int m0 = blockIdx.x * 128;
    const int n0 = blockIdx.y * 128;
    const int lane = t & 63;
    const int w = t >> 6;
    const int wm = (w >> 1) * 64, wn = (w & 1) * 64;
    const int ln = lane & 15, hi = lane >> 4;

    f32x4 acc[4][4];
#pragma unroll
    for (int mi = 0; mi < 4; ++mi)
#pragma unroll
        for (int ni = 0; ni < 4; ++ni) acc[mi][ni] = (f32x4){0.f, 0.f, 0.f, 0.f};

    for (int k0 = 0; k0 < D_; k0 += 32) {
        __syncthreads();
#pragma unroll
        for (int j = 0; j < 2; ++j) {
            const int seg = t + j * 256;
            const int row = seg >> 2, off = (seg & 3) * 8;
            s16x8 av = *(const s16x8*)&A[(size_t)(m0 + row) * D_ + k0 + off];
            *(s16x8*)&Al[row * PLDA + off] = av;
            s16x8 bv = *(const s16x8*)&Bt[(size_t)(n0 + row) * D_ + k0 + off];
            *(s16x8*)&Bl[row * PLDA + off] = bv;
        }
        __syncthreads();
        s16x8 af[4], bf[4];
#pragma unroll
        for (int i = 0; i < 4; ++i) {
            af[i] = *(const s16x8*)&Al[(wm + i * 16 + ln) * PLDA + hi * 8];
            bf[i] = *(const s16x8*)&Bl[(wn + i * 16 + ln) * PLDA + hi * 8];
        }
#pragma unroll
        for (int mi = 0; mi < 4; ++mi)
#pragma unroll
            for (int ni = 0; ni < 4; ++ni)
                acc[mi][ni] = __builtin_amdgcn_mfma_f32_16x16x32_bf16(af[mi], bf[ni], acc[mi][ni], 0, 0, 0);
    }

    const int ng_base = n0 + wn;
    const int w_idx = ng_base / D_;
    ushort_t* dst = (w_idx == 0) ? oq : (w_idx == 1) ? ok : (w_idx == 2) ? ov
                    : (w_idx == 3) ? okg : ovg;
    const int cbase = ng_base - w_idx * D_;
#pragma unroll
    for (int mi = 0; mi < 4; ++mi) {
#pragma unroll
        for (int ni = 0; ni < 4; ++ni) {
            const int c = cbase + ni * 16 + ln;
            const int h = c >> 6, d = c & 63;
#pragma unroll
            for (int r = 0; r < 4; ++r) {
                const int m = m0 + wm + mi * 16 + hi * 4 + r;
                const int b = m >> 12, s = m & 4095;
                dst[((size_t)(b * H_ + h) * S_ + s) * DH_ + d] = f2bf(acc[mi][ni][r]);
            }
        }
    }
}

// ---------------------------------------------------------------------------
// qg GEMM (fp32, tiny: only first G rows per batch).
// ---------------------------------------------------------------------------
__global__ __launch_bounds__(256) void qg_gemm(const float* __restrict__ X,
                                               const float* __restrict__ Wm,
                                               float* __restrict__ qg,
                                               float scale) {
    __shared__ float xr[D_];
    const int row = blockIdx.x;
    const int b = row / G_;
    const int g = row - b * G_;
    for (int i = threadIdx.x; i < D_; i += 256)
        xr[i] = X[((size_t)b * S_ + g) * D_ + i];
    __syncthreads();
    for (int c = threadIdx.x; c < D_; c += 256) {
        float acc = 0.f;
        for (int kk = 0; kk < D_; ++kk) acc += xr[kk] * Wm[(size_t)kk * D_ + c];
        qg[(size_t)row * D_ + c] = acc * scale;
    }
}

// ---------------------------------------------------------------------------
// Windowed attention, MFMA flash-style.  One block per (chunk, h, b);
// 4 waves x 64 queries.  13 key-tiles of 64 (tile 0 = global keys 0..7).
// ---------------------------------------------------------------------------
__global__ __launch_bounds__(256, 2) void win_mfma(const ushort_t* __restrict__ q,
                                                   const ushort_t* __restrict__ k,
                                                   const ushort_t* __restrict__ v,
                                                   const float* __restrict__ am,
                                                   float* __restrict__ out) {
    __shared__ ushort_t Kl[64 * 72];      // K rows=key, cols=dim (padded 72)
    __shared__ ushort_t Vt[64 * 72];      // V^T rows=dim, cols=key (padded 72)
    __shared__ ushort_t Pl[4][64 * 72];   // per-wave P (rows=q, cols=key)
    __shared__ float Kval[64];

    const int n = blockIdx.x, h = blockIdx.y, b = blockIdx.z;
    const int t = threadIdx.x;
    const int lane = t & 63, w = t >> 6;
    const int ln = lane & 15, hi = lane >> 4;
    const int q0 = n * W_ + w * 64;
    const size_t bh = (size_t)(b * H_ + h) * S_;

    // Q fragments (A-operand): row = l&15, k = (l>>4)*8, two K-steps.
    s16x8 qf[4][2];
#pragma unroll
    for (int mi = 0; mi < 4; ++mi)
#pragma unroll
        for (int ks = 0; ks < 2; ++ks)
            qf[mi][ks] = *(const s16x8*)&q[(bh + q0 + mi * 16 + ln) * DH_ + ks * 32 + hi * 8];

    f32x4 oacc[4][4];
    float m_run[4][4], l_run[4][4];
#pragma unroll
    for (int mi = 0; mi < 4; ++mi) {
#pragma unroll
        for (int ni = 0; ni < 4; ++ni) oacc[mi][ni] = (f32x4){0.f, 0.f, 0.f, 0.f};
#pragma unroll
        for (int r = 0; r < 4; ++r) { m_run[mi][r] = -1e30f; l_run[mi][r] = 0.f; }
    }

    const int pbase0 = n * W_ - W_;

    for (int tt = 0; tt < 13; ++tt) {
        const bool isg = (tt == 0);
        const int pbase = pbase0 + (tt - 1) * 64;
        __syncthreads();
        // ---- stage K (row-major) ----
#pragma unroll
        for (int j = 0; j < 2; ++j) {
            const int seg = t * 2 + j;
            const int row = seg >> 3, off = (seg & 7) * 8;
            const int p = isg ? row : pbase + row;
            const int pr = p < 0 ? 0 : (p >= S_ ? S_ - 1 : p);
            s16x8 kv = *(const s16x8*)&k[(bh + pr) * DH_ + off];
            *(s16x8*)&Kl[row * 72 + off] = kv;
        }
        // ---- stage V transposed ----
        {
            const int key = t & 63;
            const int d0 = (t >> 6) * 16;
            const int p = isg ? key : pbase + key;
            const int pr = p < 0 ? 0 : (p >= S_ ? S_ - 1 : p);
            const ushort_t* vr = &v[(bh + pr) * DH_ + d0];
            s16x8 a = *(const s16x8*)vr;
            s16x8 b8 = *(const s16x8*)(vr + 8);
#pragma unroll
            for (int i = 0; i < 8; ++i) {
                Vt[(d0 + i) * 72 + key] = (ushort_t)a[i];
                Vt[(d0 + 8 + i) * 72 + key] = (ushort_t)b8[i];
            }
        }
        if (t < 64) {
            float okf;
            if (isg) okf = (t < G_) ? 1.f : 0.f;
            else {
                const int p = pbase + t;
                okf = (p >= G_ && p < S_ && am[(size_t)b * S_ + p] > 0.5f) ? 1.f : 0.f;
            }
            Kval[t] = okf;
        }
        __syncthreads();

        // wave-level band skip (whole tile outside this wave's band)
        if (!isg && (pbase > q0 + 63 + W_ || pbase + 63 < q0 - W_)) continue;

        // ---- QK^T ----
        f32x4 sc[4][4];
#pragma unroll
        for (int mi = 0; mi < 4; ++mi)
#pragma unroll
            for (int ni = 0; ni < 4; ++ni) sc[mi][ni] = (f32x4){0.f, 0.f, 0.f, 0.f};
#pragma unroll
        for (int ks = 0; ks < 2; ++ks) {
            s16x8 kf[4];
#pragma unroll
            for (int ni = 0; ni < 4; ++ni)
                kf[ni] = *(const s16x8*)&Kl[(ni * 16 + ln) * 72 + ks * 32 + hi * 8];
#pragma unroll
            for (int mi = 0; mi < 4; ++mi)
#pragma unroll
                for (int ni = 0; ni < 4; ++ni)
                    sc[mi][ni] = __builtin_amdgcn_mfma_f32_16x16x32_bf16(qf[mi][ks], kf[ni], sc[mi][ni], 0, 0, 0);
        }

        // ---- mask + online softmax + P write ----
        float kvl[4]; int pc[4];
#pragma unroll
        for (int ni = 0; ni < 4; ++ni) {
            kvl[ni] = Kval[ni * 16 + ln];
            pc[ni] = pbase + ni * 16 + ln;
        }
        ushort_t* Pw = &Pl[w][0];
#pragma unroll
        for (int mi = 0; mi < 4; ++mi) {
#pragma unroll
            for (int r = 0; r < 4; ++r) {
                const int qp = q0 + mi * 16 + hi * 4 + r;
                float tmax = -1e30f;
#pragma unroll
                for (int ni = 0; ni < 4; ++ni) {
                    const bool okb = (kvl[ni] > 0.5f) &&
                                     (isg || (pc[ni] >= qp - W_ && pc[ni] <= qp + W_));
                    const float s = okb ? sc[mi][ni][r] : -1e30f;
                    sc[mi][ni][r] = s;
                    tmax = fmaxf(tmax, s);
                }
                tmax = fmaxf(tmax, __shfl_xor(tmax, 1));
                tmax = fmaxf(tmax, __shfl_xor(tmax, 2));
                tmax = fmaxf(tmax, __shfl_xor(tmax, 4));
                tmax = fmaxf(tmax, __shfl_xor(tmax, 8));
                const float mold = m_run[mi][r];
                const float mnew = fmaxf(mold, tmax);
                const float f = __expf(mold - mnew);
                float psum = 0.f;
#pragma unroll
                for (int ni = 0; ni < 4; ++ni) {
                    const float p = __expf(sc[mi][ni][r] - mnew);
                    psum += p;
                    Pw[(mi * 16 + hi * 4 + r) * 72 + ni * 16 + ln] = f2bf(p);
                }
                psum += __shfl_xor(psum, 1);
                psum += __shfl_xor(psum, 2);
                psum += __shfl_xor(psum, 4);
                psum += __shfl_xor(psum, 8);
                l_run[mi][r] = l_run[mi][r] * f + psum;
                m_run[mi][r] = mnew;
#pragma unroll
                for (int nd = 0; nd < 4; ++nd) oacc[mi][nd][r] *= f;
            }
        }

        // ---- PV ----
#pragma unroll
        for (int ksp = 0; ksp < 2; ++ksp) {
            s16x8 vf[4];
#pragma unroll
            for (int nd = 0; nd < 4; ++nd)
                vf[nd] = *(const s16x8*)&Vt[(nd * 16 + ln) * 72 + ksp * 32 + hi * 8];
#pragma unroll
            for (int mi = 0; mi < 4; ++mi) {
                s16x8 pa = *(const s16x8*)&Pw[(mi * 16 + ln) * 72 + ksp * 32 + hi * 8];
#pragma unroll
                for (int nd = 0; nd < 4; ++nd)
                    oacc[mi][nd] = __builtin_amdgcn_mfma_f32_16x16x32_bf16(pa, vf[nd], oacc[mi][nd], 0, 0, 0);
            }
        }
    }

    // ---- epilogue ----
#pragma unroll
    for (int mi = 0; mi < 4; ++mi) {
#pragma unroll
        for (int r = 0; r < 4; ++r) {
            const int qp = q0 + mi * 16 + hi * 4 + r;
            const float inv = 1.0f / l_run[mi][r];
            float* orow = &out[((size_t)b * S_ + qp) * D_ + h * DH_];
#pragma unroll
            for (int nd = 0; nd < 4; ++nd)
                orow[nd * 16 + ln] = oacc[mi][nd][r] * inv;
        }
    }
}

// ---------------------------------------------------------------------------
// Global attention rows (first G per batch).  kg/vg now bf16.
// ---------------------------------------------------------------------------
__global__ __launch_bounds__(256) void glob_attn(const float* __restrict__ qg,
                                                 const ushort_t* __restrict__ kg,
                                                 const ushort_t* __restrict__ vg,
                                                 const float* __restrict__ am,
                                                 float* __restrict__ out) {
    const int g = blockIdx.x;
    const int h = blockIdx.y;
    const int b = blockIdx.z;
    const int tid = threadIdx.x;

    __shared__ float sc[S_];
    __shared__ float qs[DH_];
    __shared__ float red[256];
    __shared__ float red2[4][DH_];

    if (tid < DH_) qs[tid] = qg[(size_t)(b * G_ + g) * D_ + h * DH_ + tid];
    __syncthreads();

    const ushort_t* __restrict__ kgb = &kg[(size_t)(b * H_ + h) * S_ * DH_];
    const ushort_t* __restrict__ vgb = &vg[(size_t)(b * H_ + h) * S_ * DH_];

    float lmax = -1e30f;
    for (int s = tid; s < S_; s += 256) {
        float acc = 0.f;
        const ushort_t* krow = &kgb[(size_t)s * DH_];
#pragma unroll
        for (int d8 = 0; d8 < 8; ++d8) {
            s16x8 kv = *(const s16x8*)&krow[d8 * 8];
#pragma unroll
            for (int i = 0; i < 8; ++i) acc += qs[d8 * 8 + i] * bf2f((ushort_t)kv[i]);
        }
        if (!(am[(size_t)b * S_ + s] > 0.5f)) acc = NEG_;
        sc[s] = acc;
        lmax = fmaxf(lmax, acc);
    }
    red[tid] = lmax;
    __syncthreads();
    for (int off = 128; off > 0; off >>= 1) {
        if (tid < off) red[tid] = fmaxf(red[tid], red[tid + off]);
        __syncthreads();
    }
    const float mx = red[0];
    __syncthreads();

    float lsum = 0.f;
    for (int s = tid; s < S_; s += 256) {
        const float e = __expf(sc[s] - mx);
        sc[s] = e;
        lsum += e;
    }
    red[tid] = lsum;
    __syncthreads();
    for (int off = 128; off > 0; off >>= 1) {
        if (tid < off) red[tid] += red[tid + off];
        __syncthreads();
    }
    const float l = red[0];
    __syncthreads();

    const int d = tid & 63;
    const int grp = tid >> 6;
    float acc = 0.f;
    for (int s = grp; s < S_; s += 4) acc += sc[s] * bf2f(vgb[(size_t)s * DH_ + d]);
    red2[grp][d] = acc;
    __syncthreads();
    if (tid < DH_) {
        const float r = (red2[0][tid] + red2[1][tid] + red2[2][tid] + red2[3][tid]) / l;
        out[((size_t)b * S_ + g) * D_ + h * DH_ + tid] = r;
    }
}

// ---------------------------------------------------------------------------
extern "C" void kernel_launch(void* const* d_in, const int* in_sizes, int n_in,
                              void* d_out, int out_size, void* d_ws, size_t ws_size,
                              hipStream_t stream) {
    (void)in_sizes; (void)n_in; (void)out_size; (void)ws_size;

    const float* hs    = (const float*)d_in[0];
    const float* amask = (const float*)d_in[1];
    const float* Wq    = (const float*)d_in[2];
    const float* Wk    = (const float*)d_in[3];
    const float* Wv    = (const float*)d_in[4];
    const float* Wqg   = (const float*)d_in[5];
    const float* Wkg   = (const float*)d_in[6];
    const float* Wvg   = (const float*)d_in[7];
    float* out = (float*)d_out;

    char* p = (char*)d_ws;
    ushort_t* hs_bf = (ushort_t*)p; p += (size_t)B_ * S_ * D_ * 2;        // 12.6 MB
    ushort_t* wt    = (ushort_t*)p; p += (size_t)5 * D_ * D_ * 2;         // 5.9 MB
    const size_t per = (size_t)B_ * H_ * S_ * DH_;
    ushort_t* qb  = (ushort_t*)p; p += per * 2;
    ushort_t* kb  = (ushort_t*)p; p += per * 2;
    ushort_t* vb  = (ushort_t*)p; p += per * 2;
    ushort_t* kgb = (ushort_t*)p; p += per * 2;
    ushort_t* vgb = (ushort_t*)p; p += per * 2;
    float* qg = (float*)p;

    convert_hs<<<(B_ * S_ * D_ / 8 + 255) / 256, 256, 0, stream>>>(hs, hs_bf, B_ * S_ * D_ / 8);
    convert_wt<<<dim3(D_ / 32, D_ / 32, 5), 256, 0, stream>>>(Wq, Wk, Wv, Wkg, Wvg, wt);
    proj_mfma<<<dim3(B_ * S_ / 128, 5 * D_ / 128), 256, 0, stream>>>(hs_bf, wt, qb, kb, vb, kgb, vgb);
    qg_gemm<<<B_ * G_, 256, 0, stream>>>(hs, Wqg, qg, 0.125f);
    win_mfma<<<dim3(S_ / W_, H_, B_), 256, 0, stream>>>(qb, kb, vb, amask, out);
    glob_attn<<<dim3(G_, H_, B_), 256, 0, stream>>>(qg, kgb, vgb, amask, out);
}

// Round 3
// 298.595 us; speedup vs baseline: 5.2728x; 2.0137x over previous
//
#include <hip/hip_runtime.h>

#define B_ 2
#define S_ 4096
#define D_ 768
#define H_ 12
#define DH_ 64
#define W_ 256
#define G_ 8
#define NEG_ (-1e9f)
#define NC_ 64
#define CK_ 64

typedef __attribute__((ext_vector_type(4))) float f32x4;
typedef __attribute__((ext_vector_type(8))) short s16x8;
typedef __attribute__((ext_vector_type(4))) short s16x4;
typedef unsigned short ushort_t;

__device__ __forceinline__ unsigned short f2bf(float f) {
    union { float f; unsigned u; } v; v.f = f;
    unsigned r = v.u + 0x7FFFu + ((v.u >> 16) & 1u);
    return (unsigned short)(r >> 16);
}
__device__ __forceinline__ float bf2f(unsigned short b) {
    union { unsigned u; float f; } v; v.u = ((unsigned)b) << 16;
    return v.f;
}

// ---------------------------------------------------------------------------
// hs fp32 -> bf16
// ---------------------------------------------------------------------------
__global__ __launch_bounds__(256) void convert_hs(const float* __restrict__ x,
                                                  ushort_t* __restrict__ y, int n8) {
    int i = blockIdx.x * 256 + threadIdx.x;
    if (i >= n8) return;
    float4 a = *(const float4*)&x[(size_t)i * 8];
    float4 c = *(const float4*)&x[(size_t)i * 8 + 4];
    s16x8 o;
    o[0] = (short)f2bf(a.x); o[1] = (short)f2bf(a.y);
    o[2] = (short)f2bf(a.z); o[3] = (short)f2bf(a.w);
    o[4] = (short)f2bf(c.x); o[5] = (short)f2bf(c.y);
    o[6] = (short)f2bf(c.z); o[7] = (short)f2bf(c.w);
    *(s16x8*)&y[(size_t)i * 8] = o;
}

// ---------------------------------------------------------------------------
// Weights: transpose+convert into Wt[w*768 + n][k] = W_w[k][n] (bf16).
// Scale 0.125 folded into Wq (w==0).
// ---------------------------------------------------------------------------
__global__ __launch_bounds__(256) void convert_wt(const float* __restrict__ W0,
                                                  const float* __restrict__ W1,
                                                  const float* __restrict__ W2,
                                                  const float* __restrict__ W3,
                                                  const float* __restrict__ W4,
                                                  ushort_t* __restrict__ wt) {
    __shared__ float tile[32][33];
    const int w = blockIdx.z;
    const float* Wsrc = (w == 0) ? W0 : (w == 1) ? W1 : (w == 2) ? W2 : (w == 3) ? W3 : W4;
    const float scl = (w == 0) ? 0.125f : 1.0f;
    const int k0 = blockIdx.x * 32;
    const int n0 = blockIdx.y * 32;
    const int t = threadIdx.x;
    const int r = t >> 3, c4 = (t & 7) * 4;
    float4 src = *(const float4*)&Wsrc[(size_t)(k0 + r) * D_ + n0 + c4];
    tile[r][c4 + 0] = src.x; tile[r][c4 + 1] = src.y;
    tile[r][c4 + 2] = src.z; tile[r][c4 + 3] = src.w;
    __syncthreads();
    s16x4 o;
    o[0] = (short)f2bf(tile[c4 + 0][r] * scl);
    o[1] = (short)f2bf(tile[c4 + 1][r] * scl);
    o[2] = (short)f2bf(tile[c4 + 2][r] * scl);
    o[3] = (short)f2bf(tile[c4 + 3][r] * scl);
    *(s16x4*)&wt[((size_t)(w * D_ + n0 + r)) * D_ + k0 + c4] = o;
}

// ---------------------------------------------------------------------------
// Fused projection GEMM (bf16 MFMA), epilogue to head layout per projection.
// ---------------------------------------------------------------------------
#define PLDA 40

__global__ __launch_bounds__(256, 2) void proj_mfma(const ushort_t* __restrict__ A,
                                                    const ushort_t* __restrict__ Bt,
                                                    ushort_t* __restrict__ oq,
                                                    ushort_t* __restrict__ ok,
                                                    ushort_t* __restrict__ ov,
                                                    ushort_t* __restrict__ okg,
                                                    ushort_t* __restrict__ ovg) {
    __shared__ ushort_t Al[128 * PLDA];
    __shared__ ushort_t Bl[128 * PLDA];
    const int t = threadIdx.x;
    const int m0 = blockIdx.x * 128;
    const int n0 = blockIdx.y * 128;
    const int lane = t & 63;
    const int w = t >> 6;
    const int wm = (w >> 1) * 64, wn = (w & 1) * 64;
    const int ln = lane & 15, hi = lane >> 4;

    f32x4 acc[4][4];
#pragma unroll
    for (int mi = 0; mi < 4; ++mi)
#pragma unroll
        for (int ni = 0; ni < 4; ++ni) acc[mi][ni] = (f32x4){0.f, 0.f, 0.f, 0.f};

    for (int k0 = 0; k0 < D_; k0 += 32) {
        __syncthreads();
#pragma unroll
        for (int j = 0; j < 2; ++j) {
            const int seg = t + j * 256;
            const int row = seg >> 2, off = (seg & 3) * 8;
            s16x8 av = *(const s16x8*)&A[(size_t)(m0 + row) * D_ + k0 + off];
            *(s16x8*)&Al[row * PLDA + off] = av;
            s16x8 bv = *(const s16x8*)&Bt[(size_t)(n0 + row) * D_ + k0 + off];
            *(s16x8*)&Bl[row * PLDA + off] = bv;
        }
        __syncthreads();
        s16x8 af[4], bf[4];
#pragma unroll
        for (int i = 0; i < 4; ++i) {
            af[i] = *(const s16x8*)&Al[(wm + i * 16 + ln) * PLDA + hi * 8];
            bf[i] = *(const s16x8*)&Bl[(wn + i * 16 + ln) * PLDA + hi * 8];
        }
#pragma unroll
        for (int mi = 0; mi < 4; ++mi)
#pragma unroll
            for (int ni = 0; ni < 4; ++ni)
                acc[mi][ni] = __builtin_amdgcn_mfma_f32_16x16x32_bf16(af[mi], bf[ni], acc[mi][ni], 0, 0, 0);
    }

    const int ng_base = n0 + wn;
    const int w_idx = ng_base / D_;
    ushort_t* dst = (w_idx == 0) ? oq : (w_idx == 1) ? ok : (w_idx == 2) ? ov
                    : (w_idx == 3) ? okg : ovg;
    const int cbase = ng_base - w_idx * D_;
#pragma unroll
    for (int mi = 0; mi < 4; ++mi) {
#pragma unroll
        for (int ni = 0; ni < 4; ++ni) {
            const int c = cbase + ni * 16 + ln;
            const int h = c >> 6, d = c & 63;
#pragma unroll
            for (int r = 0; r < 4; ++r) {
                const int m = m0 + wm + mi * 16 + hi * 4 + r;
                const int b = m >> 12, s = m & 4095;
                dst[((size_t)(b * H_ + h) * S_ + s) * DH_ + d] = f2bf(acc[mi][ni][r]);
            }
        }
    }
}

// ---------------------------------------------------------------------------
// qg GEMM: 16 rows total. grid (8 row-pairs, 6 col-tiles of 128).
// ---------------------------------------------------------------------------
__global__ __launch_bounds__(256) void qg_gemm(const float* __restrict__ X,
                                               const float* __restrict__ Wm,
                                               float* __restrict__ qg) {
    const int rp = blockIdx.x;
    const int c0 = blockIdx.y * 128;
    const int t = threadIdx.x;
    const int r = t >> 7, cl = t & 127;
    __shared__ float xr[2][D_];
    for (int i = t; i < 2 * D_; i += 256) {
        const int rr = i / D_, kk = i - rr * D_;
        const int row = rp * 2 + rr;
        const int b = row >> 3, g = row & 7;
        xr[rr][kk] = X[((size_t)b * S_ + g) * D_ + kk];
    }
    __syncthreads();
    float a0 = 0.f, a1 = 0.f, a2 = 0.f, a3 = 0.f;
    const float* wp = &Wm[c0 + cl];
    for (int kk = 0; kk < D_; kk += 4) {
        a0 += xr[r][kk + 0] * wp[(size_t)(kk + 0) * D_];
        a1 += xr[r][kk + 1] * wp[(size_t)(kk + 1) * D_];
        a2 += xr[r][kk + 2] * wp[(size_t)(kk + 2) * D_];
        a3 += xr[r][kk + 3] * wp[(size_t)(kk + 3) * D_];
    }
    const int row = rp * 2 + r;
    qg[(size_t)row * D_ + c0 + cl] = (a0 + a1 + a2 + a3) * 0.125f;
}

// ---------------------------------------------------------------------------
// Windowed attention, MFMA flash-style (unchanged from round 2).
// ---------------------------------------------------------------------------
__global__ __launch_bounds__(256, 2) void win_mfma(const ushort_t* __restrict__ q,
                                                   const ushort_t* __restrict__ k,
                                                   const ushort_t* __restrict__ v,
                                                   const float* __restrict__ am,
                                                   float* __restrict__ out) {
    __shared__ ushort_t Kl[64 * 72];
    __shared__ ushort_t Vt[64 * 72];
    __shared__ ushort_t Pl[4][64 * 72];
    __shared__ float Kval[64];

    const int n = blockIdx.x, h = blockIdx.y, b = blockIdx.z;
    const int t = threadIdx.x;
    const int lane = t & 63, w = t >> 6;
    const int ln = lane & 15, hi = lane >> 4;
    const int q0 = n * W_ + w * 64;
    const size_t bh = (size_t)(b * H_ + h) * S_;

    s16x8 qf[4][2];
#pragma unroll
    for (int mi = 0; mi < 4; ++mi)
#pragma unroll
        for (int ks = 0; ks < 2; ++ks)
            qf[mi][ks] = *(const s16x8*)&q[(bh + q0 + mi * 16 + ln) * DH_ + ks * 32 + hi * 8];

    f32x4 oacc[4][4];
    float m_run[4][4], l_run[4][4];
#pragma unroll
    for (int mi = 0; mi < 4; ++mi) {
#pragma unroll
        for (int ni = 0; ni < 4; ++ni) oacc[mi][ni] = (f32x4){0.f, 0.f, 0.f, 0.f};
#pragma unroll
        for (int r = 0; r < 4; ++r) { m_run[mi][r] = -1e30f; l_run[mi][r] = 0.f; }
    }

    const int pbase0 = n * W_ - W_;

    for (int tt = 0; tt < 13; ++tt) {
        const bool isg = (tt == 0);
        const int pbase = pbase0 + (tt - 1) * 64;
        __syncthreads();
#pragma unroll
        for (int j = 0; j < 2; ++j) {
            const int seg = t * 2 + j;
            const int row = seg >> 3, off = (seg & 7) * 8;
            const int p = isg ? row : pbase + row;
            const int pr = p < 0 ? 0 : (p >= S_ ? S_ - 1 : p);
            s16x8 kv = *(const s16x8*)&k[(bh + pr) * DH_ + off];
            *(s16x8*)&Kl[row * 72 + off] = kv;
        }
        {
            const int key = t & 63;
            const int d0 = (t >> 6) * 16;
            const int p = isg ? key : pbase + key;
            const int pr = p < 0 ? 0 : (p >= S_ ? S_ - 1 : p);
            const ushort_t* vr = &v[(bh + pr) * DH_ + d0];
            s16x8 a = *(const s16x8*)vr;
            s16x8 b8 = *(const s16x8*)(vr + 8);
#pragma unroll
            for (int i = 0; i < 8; ++i) {
                Vt[(d0 + i) * 72 + key] = (ushort_t)a[i];
                Vt[(d0 + 8 + i) * 72 + key] = (ushort_t)b8[i];
            }
        }
        if (t < 64) {
            float okf;
            if (isg) okf = (t < G_) ? 1.f : 0.f;
            else {
                const int p = pbase + t;
                okf = (p >= G_ && p < S_ && am[(size_t)b * S_ + p] > 0.5f) ? 1.f : 0.f;
            }
            Kval[t] = okf;
        }
        __syncthreads();

        if (!isg && (pbase > q0 + 63 + W_ || pbase + 63 < q0 - W_)) continue;

        f32x4 sc[4][4];
#pragma unroll
        for (int mi = 0; mi < 4; ++mi)
#pragma unroll
            for (int ni = 0; ni < 4; ++ni) sc[mi][ni] = (f32x4){0.f, 0.f, 0.f, 0.f};
#pragma unroll
        for (int ks = 0; ks < 2; ++ks) {
            s16x8 kf[4];
#pragma unroll
            for (int ni = 0; ni < 4; ++ni)
                kf[ni] = *(const s16x8*)&Kl[(ni * 16 + ln) * 72 + ks * 32 + hi * 8];
#pragma unroll
            for (int mi = 0; mi < 4; ++mi)
#pragma unroll
                for (int ni = 0; ni < 4; ++ni)
                    sc[mi][ni] = __builtin_amdgcn_mfma_f32_16x16x32_bf16(qf[mi][ks], kf[ni], sc[mi][ni], 0, 0, 0);
        }

        float kvl[4]; int pc[4];
#pragma unroll
        for (int ni = 0; ni < 4; ++ni) {
            kvl[ni] = Kval[ni * 16 + ln];
            pc[ni] = pbase + ni * 16 + ln;
        }
        ushort_t* Pw = &Pl[w][0];
#pragma unroll
        for (int mi = 0; mi < 4; ++mi) {
#pragma unroll
            for (int r = 0; r < 4; ++r) {
                const int qp = q0 + mi * 16 + hi * 4 + r;
                float tmax = -1e30f;
#pragma unroll
                for (int ni = 0; ni < 4; ++ni) {
                    const bool okb = (kvl[ni] > 0.5f) &&
                                     (isg || (pc[ni] >= qp - W_ && pc[ni] <= qp + W_));
                    const float s = okb ? sc[mi][ni][r] : -1e30f;
                    sc[mi][ni][r] = s;
                    tmax = fmaxf(tmax, s);
                }
                tmax = fmaxf(tmax, __shfl_xor(tmax, 1));
                tmax = fmaxf(tmax, __shfl_xor(tmax, 2));
                tmax = fmaxf(tmax, __shfl_xor(tmax, 4));
                tmax = fmaxf(tmax, __shfl_xor(tmax, 8));
                const float mold = m_run[mi][r];
                const float mnew = fmaxf(mold, tmax);
                const float f = __expf(mold - mnew);
                float psum = 0.f;
#pragma unroll
                for (int ni = 0; ni < 4; ++ni) {
                    const float p = __expf(sc[mi][ni][r] - mnew);
                    psum += p;
                    Pw[(mi * 16 + hi * 4 + r) * 72 + ni * 16 + ln] = f2bf(p);
                }
                psum += __shfl_xor(psum, 1);
                psum += __shfl_xor(psum, 2);
                psum += __shfl_xor(psum, 4);
                psum += __shfl_xor(psum, 8);
                l_run[mi][r] = l_run[mi][r] * f + psum;
                m_run[mi][r] = mnew;
#pragma unroll
                for (int nd = 0; nd < 4; ++nd) oacc[mi][nd][r] *= f;
            }
        }

#pragma unroll
        for (int ksp = 0; ksp < 2; ++ksp) {
            s16x8 vf[4];
#pragma unroll
            for (int nd = 0; nd < 4; ++nd)
                vf[nd] = *(const s16x8*)&Vt[(nd * 16 + ln) * 72 + ksp * 32 + hi * 8];
#pragma unroll
            for (int mi = 0; mi < 4; ++mi) {
                s16x8 pa = *(const s16x8*)&Pw[(mi * 16 + ln) * 72 + ksp * 32 + hi * 8];
#pragma unroll
                for (int nd = 0; nd < 4; ++nd)
                    oacc[mi][nd] = __builtin_amdgcn_mfma_f32_16x16x32_bf16(pa, vf[nd], oacc[mi][nd], 0, 0, 0);
            }
        }
    }

#pragma unroll
    for (int mi = 0; mi < 4; ++mi) {
#pragma unroll
        for (int r = 0; r < 4; ++r) {
            const int qp = q0 + mi * 16 + hi * 4 + r;
            const float inv = 1.0f / l_run[mi][r];
            float* orow = &out[((size_t)b * S_ + qp) * D_ + h * DH_];
#pragma unroll
            for (int nd = 0; nd < 4; ++nd)
                orow[nd * 16 + ln] = oacc[mi][nd][r] * inv;
        }
    }
}

// ---------------------------------------------------------------------------
// Global attention phase A: split-K over 64-key chunks.
// grid (NC_, H, B), 256 threads.  Writes per-chunk partials.
// ---------------------------------------------------------------------------
__global__ __launch_bounds__(256) void glob_partial(const float* __restrict__ qg,
                                                    const ushort_t* __restrict__ kg,
                                                    const ushort_t* __restrict__ vg,
                                                    const float* __restrict__ am,
                                                    float* __restrict__ pout,
                                                    float* __restrict__ pm,
                                                    float* __restrict__ pl) {
    const int c = blockIdx.x, h = blockIdx.y, b = blockIdx.z;
    const int t = threadIdx.x;
    const int bh = b * H_ + h;
    const size_t base = (size_t)bh * S_ * DH_;
    const int jg0 = c * CK_;

    __shared__ float qs[G_][DH_];
    __shared__ float kt[CK_][69];
    __shared__ float vt[CK_][68];
    __shared__ float ps[G_][CK_];

    for (int i = t; i < G_ * DH_; i += 256)
        qs[i >> 6][i & 63] = qg[(size_t)(b * G_ + (i >> 6)) * D_ + h * DH_ + (i & 63)];
    {
        const int row = t >> 2, off = (t & 3) * 16;
        const ushort_t* kr = &kg[base + (size_t)(jg0 + row) * DH_ + off];
        const ushort_t* vr = &vg[base + (size_t)(jg0 + row) * DH_ + off];
        s16x8 ka = *(const s16x8*)kr;
        s16x8 kb2 = *(const s16x8*)(kr + 8);
        s16x8 va = *(const s16x8*)vr;
        s16x8 vb = *(const s16x8*)(vr + 8);
#pragma unroll
        for (int i = 0; i < 8; ++i) {
            kt[row][off + i] = bf2f((ushort_t)ka[i]);
            kt[row][off + 8 + i] = bf2f((ushort_t)kb2[i]);
            vt[row][off + i] = bf2f((ushort_t)va[i]);
            vt[row][off + 8 + i] = bf2f((ushort_t)vb[i]);
        }
    }
    __syncthreads();

    // scores: thread group of 32 per g; each thread keys jl, jl+32.
    const int g = t >> 5, jl = t & 31;
    float sc0 = 0.f, sc1 = 0.f;
#pragma unroll 8
    for (int d = 0; d < DH_; ++d) {
        const float qv = qs[g][d];
        sc0 += qv * kt[jl][d];
        sc1 += qv * kt[jl + 32][d];
    }
    if (!(am[(size_t)b * S_ + jg0 + jl] > 0.5f)) sc0 = NEG_;
    if (!(am[(size_t)b * S_ + jg0 + jl + 32] > 0.5f)) sc1 = NEG_;

    float mm = fmaxf(sc0, sc1);
    mm = fmaxf(mm, __shfl_xor(mm, 1));
    mm = fmaxf(mm, __shfl_xor(mm, 2));
    mm = fmaxf(mm, __shfl_xor(mm, 4));
    mm = fmaxf(mm, __shfl_xor(mm, 8));
    mm = fmaxf(mm, __shfl_xor(mm, 16));
    const float p0 = __expf(sc0 - mm);
    const float p1 = __expf(sc1 - mm);
    float ls = p0 + p1;
    ls += __shfl_xor(ls, 1);
    ls += __shfl_xor(ls, 2);
    ls += __shfl_xor(ls, 4);
    ls += __shfl_xor(ls, 8);
    ls += __shfl_xor(ls, 16);
    ps[g][jl] = p0;
    ps[g][jl + 32] = p1;
    if (jl == 0) {
        pm[((size_t)bh * NC_ + c) * G_ + g] = mm;
        pl[((size_t)bh * NC_ + c) * G_ + g] = ls;
    }
    __syncthreads();

    // PV partial: thread -> (g, d), 2 passes.
#pragma unroll
    for (int pass = 0; pass < 2; ++pass) {
        const int gg = (t >> 6) + pass * 4;
        const int d = t & 63;
        float acc = 0.f;
#pragma unroll 8
        for (int j = 0; j < CK_; ++j) acc += ps[gg][j] * vt[j][d];
        pout[(((size_t)bh * NC_ + c) * G_ + gg) * DH_ + d] = acc;
    }
}

// ---------------------------------------------------------------------------
// Global attention phase B: combine chunks, write first-G output rows.
// grid (B*H), 256 threads.
// ---------------------------------------------------------------------------
__global__ __launch_bounds__(256) void glob_reduce(const float* __restrict__ pout,
                                                   const float* __restrict__ pm,
                                                   const float* __restrict__ pl,
                                                   float* __restrict__ out) {
    const int bh = blockIdx.x;
    const int b = bh / H_, h = bh - b * H_;
    const int t = threadIdx.x;

    __shared__ float wc[G_][NC_];
    __shared__ float wsum[G_];

    const int g = t >> 5, cl = t & 31;
    const float m0 = pm[((size_t)bh * NC_ + cl) * G_ + g];
    const float m1 = pm[((size_t)bh * NC_ + cl + 32) * G_ + g];
    float M = fmaxf(m0, m1);
    M = fmaxf(M, __shfl_xor(M, 1));
    M = fmaxf(M, __shfl_xor(M, 2));
    M = fmaxf(M, __shfl_xor(M, 4));
    M = fmaxf(M, __shfl_xor(M, 8));
    M = fmaxf(M, __shfl_xor(M, 16));
    const float w0 = __expf(m0 - M);
    const float w1 = __expf(m1 - M);
    float S = w0 * pl[((size_t)bh * NC_ + cl) * G_ + g] +
              w1 * pl[((size_t)bh * NC_ + cl + 32) * G_ + g];
    S += __shfl_xor(S, 1);
    S += __shfl_xor(S, 2);
    S += __shfl_xor(S, 4);
    S += __shfl_xor(S, 8);
    S += __shfl_xor(S, 16);
    wc[g][cl] = w0;
    wc[g][cl + 32] = w1;
    if (cl == 0) wsum[g] = S;
    __syncthreads();

#pragma unroll
    for (int pass = 0; pass < 2; ++pass) {
        const int gg = (t >> 6) + pass * 4;
        const int d = t & 63;
        float acc = 0.f;
        for (int c2 = 0; c2 < NC_; ++c2)
            acc += wc[gg][c2] * pout[(((size_t)bh * NC_ + c2) * G_ + gg) * DH_ + d];
        out[((size_t)b * S_ + gg) * D_ + h * DH_ + d] = acc / wsum[gg];
    }
}

// ---------------------------------------------------------------------------
extern "C" void kernel_launch(void* const* d_in, const int* in_sizes, int n_in,
                              void* d_out, int out_size, void* d_ws, size_t ws_size,
                              hipStream_t stream) {
    (void)in_sizes; (void)n_in; (void)out_size; (void)ws_size;

    const float* hs    = (const float*)d_in[0];
    const float* amask = (const float*)d_in[1];
    const float* Wq    = (const float*)d_in[2];
    const float* Wk    = (const float*)d_in[3];
    const float* Wv    = (const float*)d_in[4];
    const float* Wqg   = (const float*)d_in[5];
    const float* Wkg   = (const float*)d_in[6];
    const float* Wvg   = (const float*)d_in[7];
    float* out = (float*)d_out;

    char* p = (char*)d_ws;
    ushort_t* hs_bf = (ushort_t*)p; p += (size_t)B_ * S_ * D_ * 2;
    ushort_t* wt    = (ushort_t*)p; p += (size_t)5 * D_ * D_ * 2;
    const size_t per = (size_t)B_ * H_ * S_ * DH_;
    ushort_t* qb  = (ushort_t*)p; p += per * 2;
    ushort_t* kb  = (ushort_t*)p; p += per * 2;
    ushort_t* vb  = (ushort_t*)p; p += per * 2;
    ushort_t* kgb = (ushort_t*)p; p += per * 2;
    ushort_t* vgb = (ushort_t*)p; p += per * 2;
    float* qg   = (float*)p; p += (size_t)B_ * G_ * D_ * 4;
    float* pout = (float*)p; p += (size_t)B_ * H_ * NC_ * G_ * DH_ * 4;
    float* pm   = (float*)p; p += (size_t)B_ * H_ * NC_ * G_ * 4;
    float* pl   = (float*)p;

    convert_hs<<<(B_ * S_ * D_ / 8 + 255) / 256, 256, 0, stream>>>(hs, hs_bf, B_ * S_ * D_ / 8);
    convert_wt<<<dim3(D_ / 32, D_ / 32, 5), 256, 0, stream>>>(Wq, Wk, Wv, Wkg, Wvg, wt);
    proj_mfma<<<dim3(B_ * S_ / 128, 5 * D_ / 128), 256, 0, stream>>>(hs_bf, wt, qb, kb, vb, kgb, vgb);
    qg_gemm<<<dim3(B_ * G_ / 2, D_ / 128), 256, 0, stream>>>(hs, Wqg, qg);
    win_mfma<<<dim3(S_ / W_, H_, B_), 256, 0, stream>>>(qb, kb, vb, amask, out);
    glob_partial<<<dim3(NC_, H_, B_), 256, 0, stream>>>(qg, kgb, vgb, amask, pout, pm, pl);
    glob_reduce<<<B_ * H_, 256, 0, stream>>>(pout, pm, pl, out);
}

// Round 4
// 208.321 us; speedup vs baseline: 7.5578x; 1.4333x over previous
//
#include <hip/hip_runtime.h>

#define B_ 2
#define S_ 4096
#define D_ 768
#define H_ 12
#define DH_ 64
#define W_ 256
#define G_ 8
#define NEG_ (-1e9f)
#define NC_ 64
#define CK_ 64

typedef __attribute__((ext_vector_type(4))) float f32x4;
typedef __attribute__((ext_vector_type(16))) float f32x16;
typedef __attribute__((ext_vector_type(8))) short s16x8;
typedef __attribute__((ext_vector_type(4))) short s16x4;
typedef unsigned short ushort_t;

__device__ __forceinline__ unsigned short f2bf(float f) {
    union { float f; unsigned u; } v; v.f = f;
    unsigned r = v.u + 0x7FFFu + ((v.u >> 16) & 1u);
    return (unsigned short)(r >> 16);
}
__device__ __forceinline__ float bf2f(unsigned short b) {
    union { unsigned u; float f; } v; v.u = ((unsigned)b) << 16;
    return v.f;
}
__device__ __forceinline__ unsigned cvtpk_bf16(float lo, float hi) {
    unsigned r;
    asm("v_cvt_pk_bf16_f32 %0, %1, %2" : "=v"(r) : "v"(lo), "v"(hi));
    return r;
}

// ---------------------------------------------------------------------------
// hs fp32 -> bf16
// ---------------------------------------------------------------------------
__global__ __launch_bounds__(256) void convert_hs(const float* __restrict__ x,
                                                  ushort_t* __restrict__ y, int n8) {
    int i = blockIdx.x * 256 + threadIdx.x;
    if (i >= n8) return;
    float4 a = *(const float4*)&x[(size_t)i * 8];
    float4 c = *(const float4*)&x[(size_t)i * 8 + 4];
    s16x8 o;
    o[0] = (short)f2bf(a.x); o[1] = (short)f2bf(a.y);
    o[2] = (short)f2bf(a.z); o[3] = (short)f2bf(a.w);
    o[4] = (short)f2bf(c.x); o[5] = (short)f2bf(c.y);
    o[6] = (short)f2bf(c.z); o[7] = (short)f2bf(c.w);
    *(s16x8*)&y[(size_t)i * 8] = o;
}

// ---------------------------------------------------------------------------
// Weights: transpose+convert into Wt[w*768 + n][k] (bf16), 0.125 into Wq.
// ---------------------------------------------------------------------------
__global__ __launch_bounds__(256) void convert_wt(const float* __restrict__ W0,
                                                  const float* __restrict__ W1,
                                                  const float* __restrict__ W2,
                                                  const float* __restrict__ W3,
                                                  const float* __restrict__ W4,
                                                  ushort_t* __restrict__ wt) {
    __shared__ float tile[32][33];
    const int w = blockIdx.z;
    const float* Wsrc = (w == 0) ? W0 : (w == 1) ? W1 : (w == 2) ? W2 : (w == 3) ? W3 : W4;
    const float scl = (w == 0) ? 0.125f : 1.0f;
    const int k0 = blockIdx.x * 32;
    const int n0 = blockIdx.y * 32;
    const int t = threadIdx.x;
    const int r = t >> 3, c4 = (t & 7) * 4;
    float4 src = *(const float4*)&Wsrc[(size_t)(k0 + r) * D_ + n0 + c4];
    tile[r][c4 + 0] = src.x; tile[r][c4 + 1] = src.y;
    tile[r][c4 + 2] = src.z; tile[r][c4 + 3] = src.w;
    __syncthreads();
    s16x4 o;
    o[0] = (short)f2bf(tile[c4 + 0][r] * scl);
    o[1] = (short)f2bf(tile[c4 + 1][r] * scl);
    o[2] = (short)f2bf(tile[c4 + 2][r] * scl);
    o[3] = (short)f2bf(tile[c4 + 3][r] * scl);
    *(s16x4*)&wt[((size_t)(w * D_ + n0 + r)) * D_ + k0 + c4] = o;
}

// ---------------------------------------------------------------------------
// Fused projection GEMM (bf16 MFMA), epilogue to head layout per projection.
// ---------------------------------------------------------------------------
#define PLDA 40

__global__ __launch_bounds__(256, 2) void proj_mfma(const ushort_t* __restrict__ A,
                                                    const ushort_t* __restrict__ Bt,
                                                    ushort_t* __restrict__ oq,
                                                    ushort_t* __restrict__ ok,
                                                    ushort_t* __restrict__ ov,
                                                    ushort_t* __restrict__ okg,
                                                    ushort_t* __restrict__ ovg) {
    __shared__ ushort_t Al[128 * PLDA];
    __shared__ ushort_t Bl[128 * PLDA];
    const int t = threadIdx.x;
    const int m0 = blockIdx.x * 128;
    const int n0 = blockIdx.y * 128;
    const int lane = t & 63;
    const int w = t >> 6;
    const int wm = (w >> 1) * 64, wn = (w & 1) * 64;
    const int ln = lane & 15, hi = lane >> 4;

    f32x4 acc[4][4];
#pragma unroll
    for (int mi = 0; mi < 4; ++mi)
#pragma unroll
        for (int ni = 0; ni < 4; ++ni) acc[mi][ni] = (f32x4){0.f, 0.f, 0.f, 0.f};

    for (int k0 = 0; k0 < D_; k0 += 32) {
        __syncthreads();
#pragma unroll
        for (int j = 0; j < 2; ++j) {
            const int seg = t + j * 256;
            const int row = seg >> 2, off = (seg & 3) * 8;
            s16x8 av = *(const s16x8*)&A[(size_t)(m0 + row) * D_ + k0 + off];
            *(s16x8*)&Al[row * PLDA + off] = av;
            s16x8 bv = *(const s16x8*)&Bt[(size_t)(n0 + row) * D_ + k0 + off];
            *(s16x8*)&Bl[row * PLDA + off] = bv;
        }
        __syncthreads();
        s16x8 af[4], bf[4];
#pragma unroll
        for (int i = 0; i < 4; ++i) {
            af[i] = *(const s16x8*)&Al[(wm + i * 16 + ln) * PLDA + hi * 8];
            bf[i] = *(const s16x8*)&Bl[(wn + i * 16 + ln) * PLDA + hi * 8];
        }
#pragma unroll
        for (int mi = 0; mi < 4; ++mi)
#pragma unroll
            for (int ni = 0; ni < 4; ++ni)
                acc[mi][ni] = __builtin_amdgcn_mfma_f32_16x16x32_bf16(af[mi], bf[ni], acc[mi][ni], 0, 0, 0);
    }

    const int ng_base = n0 + wn;
    const int w_idx = ng_base / D_;
    ushort_t* dst = (w_idx == 0) ? oq : (w_idx == 1) ? ok : (w_idx == 2) ? ov
                    : (w_idx == 3) ? okg : ovg;
    const int cbase = ng_base - w_idx * D_;
#pragma unroll
    for (int mi = 0; mi < 4; ++mi) {
#pragma unroll
        for (int ni = 0; ni < 4; ++ni) {
            const int c = cbase + ni * 16 + ln;
            const int h = c >> 6, d = c & 63;
#pragma unroll
            for (int r = 0; r < 4; ++r) {
                const int m = m0 + wm + mi * 16 + hi * 4 + r;
                const int b = m >> 12, s = m & 4095;
                dst[((size_t)(b * H_ + h) * S_ + s) * DH_ + d] = f2bf(acc[mi][ni][r]);
            }
        }
    }
}

// ---------------------------------------------------------------------------
// qg GEMM (tiny).
// ---------------------------------------------------------------------------
__global__ __launch_bounds__(256) void qg_gemm(const float* __restrict__ X,
                                               const float* __restrict__ Wm,
                                               float* __restrict__ qg) {
    const int rp = blockIdx.x;
    const int c0 = blockIdx.y * 128;
    const int t = threadIdx.x;
    const int r = t >> 7, cl = t & 127;
    __shared__ float xr[2][D_];
    for (int i = t; i < 2 * D_; i += 256) {
        const int rr = i / D_, kk = i - rr * D_;
        const int row = rp * 2 + rr;
        const int b = row >> 3, g = row & 7;
        xr[rr][kk] = X[((size_t)b * S_ + g) * D_ + kk];
    }
    __syncthreads();
    float a0 = 0.f, a1 = 0.f, a2 = 0.f, a3 = 0.f;
    const float* wp = &Wm[c0 + cl];
    for (int kk = 0; kk < D_; kk += 4) {
        a0 += xr[r][kk + 0] * wp[(size_t)(kk + 0) * D_];
        a1 += xr[r][kk + 1] * wp[(size_t)(kk + 1) * D_];
        a2 += xr[r][kk + 2] * wp[(size_t)(kk + 2) * D_];
        a3 += xr[r][kk + 3] * wp[(size_t)(kk + 3) * D_];
    }
    const int row = rp * 2 + r;
    qg[(size_t)row * D_ + c0 + cl] = (a0 + a1 + a2 + a3) * 0.125f;
}

// ---------------------------------------------------------------------------
// Windowed attention: 8 waves x 32 queries, 32x32x16 MFMA, swapped operands.
// QK^T: mfma(K, Q) -> S^T[key][q] (col=lane&31=q, row=(reg&3)+8*(reg>>2)+4*h5).
// PV:   mfma(V^T, P) -> O^T[d][q]  (softmax state m/l and rescale lane-local).
// 13 key tiles of 64 (tile 0 = global keys, only keys<8 valid).
// ---------------------------------------------------------------------------
#define KVST 72   // u16 row stride for K / V^T LDS (16B aligned)

__global__ __launch_bounds__(512) void win_mfma(const ushort_t* __restrict__ q,
                                                const ushort_t* __restrict__ k,
                                                const ushort_t* __restrict__ v,
                                                const float* __restrict__ am,
                                                float* __restrict__ out) {
    __shared__ char smem[34816];             // max(staging 18440, epilogue 34816)
    ushort_t* Kl = (ushort_t*)smem;          // [64][KVST]
    ushort_t* Vt = Kl + 64 * KVST;           // [64 d][KVST keys]
    unsigned* Mv = (unsigned*)(Vt + 64 * KVST);
    float* Ow = (float*)smem;                // epilogue: 4 waves x [32][68]

    const int n = blockIdx.x, h = blockIdx.y, b = blockIdx.z;
    const int t = threadIdx.x;
    const int lane = t & 63, w = t >> 6;
    const int l31 = lane & 31, h5 = lane >> 5;
    const int q0w = n * W_ + w * 32;
    const int q_abs = q0w + l31;
    const size_t bh = (size_t)(b * H_ + h) * S_;

    // Q as B-operand (Q^T fragments): lane value j = Q[q_abs][ks*16 + 8*h5 + j].
    s16x8 qf[4];
#pragma unroll
    for (int ks = 0; ks < 4; ++ks)
        qf[ks] = *(const s16x8*)&q[(bh + q_abs) * DH_ + ks * 16 + 8 * h5];

    f32x16 oacc[2];
#pragma unroll
    for (int dt = 0; dt < 2; ++dt)
#pragma unroll
        for (int i = 0; i < 16; ++i) oacc[dt][i] = 0.f;
    float m_run = -1e30f, l_run = 0.f;

    const int srow = t >> 3, soff = (t & 7) * 8;

    for (int tt = 0; tt < 13; ++tt) {
        const bool isg = (tt == 0);
        const int pbase = n * W_ - W_ + (tt - 1) * 64;
        __syncthreads();
        // ---- stage K row-major + V transposed (coalesced global reads) ----
        {
            const int p = isg ? srow : pbase + srow;
            const int pr = p < 0 ? 0 : (p >= S_ ? S_ - 1 : p);
            s16x8 kv = *(const s16x8*)&k[(bh + pr) * DH_ + soff];
            *(s16x8*)&Kl[srow * KVST + soff] = kv;
            s16x8 vv = *(const s16x8*)&v[(bh + pr) * DH_ + soff];
#pragma unroll
            for (int i = 0; i < 8; ++i) Vt[(soff + i) * KVST + srow] = (ushort_t)vv[i];
        }
        if (w == 0) {
            const int p2 = isg ? lane : pbase + lane;
            const bool ok = isg ? (lane < G_)
                                : (p2 >= G_ && p2 < S_ && am[(size_t)b * S_ + p2] > 0.5f);
            unsigned long long bal = __ballot(ok);
            if (lane == 0) { Mv[0] = (unsigned)bal; Mv[1] = (unsigned)(bal >> 32); }
        }
        __syncthreads();

        // wave-level band skip
        if (!isg && (pbase > q0w + 31 + W_ || pbase + 63 < q0w - W_)) continue;

        // ---- QK^T (swapped) ----
        f32x16 sc[2];
#pragma unroll
        for (int st = 0; st < 2; ++st)
#pragma unroll
            for (int i = 0; i < 16; ++i) sc[st][i] = 0.f;
#pragma unroll
        for (int st = 0; st < 2; ++st)
#pragma unroll
            for (int ks = 0; ks < 4; ++ks) {
                s16x8 kf = *(const s16x8*)&Kl[(st * 32 + l31) * KVST + ks * 16 + 8 * h5];
                sc[st] = __builtin_amdgcn_mfma_f32_32x32x16_bf16(kf, qf[ks], sc[st], 0, 0, 0);
            }

        // ---- mask + online softmax (lane-local; 1 cross-lane hop) ----
        const unsigned mv0 = Mv[0], mv1 = Mv[1];
        float tmax = -1e30f;
#pragma unroll
        for (int st = 0; st < 2; ++st)
#pragma unroll
            for (int reg = 0; reg < 16; ++reg) {
                const int cst = (reg & 3) + 8 * (reg >> 2);
                bool valid;
                if (isg) {
                    valid = (st == 0) && (cst < 8);   // crow=cst+4h5 < 8 iff cst < 8
                } else {
                    const int crow = cst + 4 * h5;
                    const int key_abs = pbase + st * 32 + crow;
                    const unsigned mvx = (st == 0) ? mv0 : mv1;
                    valid = ((mvx >> crow) & 1u) &&
                            (key_abs >= q_abs - W_) && (key_abs <= q_abs + W_);
                }
                const float s = valid ? sc[st][reg] : -1e30f;
                sc[st][reg] = s;
                tmax = fmaxf(tmax, s);
            }
        tmax = fmaxf(tmax, __shfl_xor(tmax, 32));
        const float mnew = fmaxf(m_run, tmax);
        const float f = __expf(m_run - mnew);
        float psum = 0.f;
#pragma unroll
        for (int st = 0; st < 2; ++st)
#pragma unroll
            for (int reg = 0; reg < 16; ++reg) {
                const float p = __expf(sc[st][reg] - mnew);
                sc[st][reg] = p;
                psum += p;
            }
        psum += __shfl_xor(psum, 32);
        l_run = l_run * f + psum;
        m_run = mnew;
#pragma unroll
        for (int dt = 0; dt < 2; ++dt)
#pragma unroll
            for (int i = 0; i < 16; ++i) oacc[dt][i] *= f;

        // ---- P -> bf16 B-fragments (cvt_pk + partner exchange) + PV ----
#pragma unroll
        for (int ks = 0; ks < 4; ++ks) {
            const int st = ks >> 1, k8 = (ks & 1) * 8;
            // own packed pairs: A=(base0,1) B=(base2,3) C=(base8,9) D=(base10,11)
            const unsigned Au = cvtpk_bf16(sc[st][k8 + 0], sc[st][k8 + 1]);
            const unsigned Bu = cvtpk_bf16(sc[st][k8 + 2], sc[st][k8 + 3]);
            const unsigned Cu = cvtpk_bf16(sc[st][k8 + 4], sc[st][k8 + 5]);
            const unsigned Du = cvtpk_bf16(sc[st][k8 + 6], sc[st][k8 + 7]);
            // h5=0 sends C,D (keys 8-11); h5=1 sends A,B (keys 4-7)
            const unsigned send0 = h5 ? Au : Cu;
            const unsigned send1 = h5 ? Bu : Du;
            const unsigned recv0 = __shfl_xor((int)send0, 32);
            const unsigned recv1 = __shfl_xor((int)send1, 32);
            union { unsigned u[4]; s16x8 v8; } pu;
            pu.u[0] = h5 ? recv0 : Au;   // keys 8h5+0,1
            pu.u[1] = h5 ? recv1 : Bu;   // keys 8h5+2,3
            pu.u[2] = h5 ? Cu : recv0;   // keys 8h5+4,5
            pu.u[3] = h5 ? Du : recv1;   // keys 8h5+6,7
#pragma unroll
            for (int dt = 0; dt < 2; ++dt) {
                s16x8 vf = *(const s16x8*)&Vt[(dt * 32 + l31) * KVST + ks * 16 + 8 * h5];
                oacc[dt] = __builtin_amdgcn_mfma_f32_32x32x16_bf16(vf, pu.v8, oacc[dt], 0, 0, 0);
            }
        }
    }

    // ---- epilogue: O^T -> O via LDS (2 rounds of 4 waves), coalesced store ----
    const float inv = 1.0f / l_run;
    for (int rnd = 0; rnd < 2; ++rnd) {
        __syncthreads();
        if ((w >> 2) == rnd) {
            float* OwW = Ow + (w & 3) * 32 * 68;
#pragma unroll
            for (int dt = 0; dt < 2; ++dt)
#pragma unroll
                for (int reg = 0; reg < 16; ++reg) {
                    const int d = dt * 32 + (reg & 3) + 8 * (reg >> 2) + 4 * h5;
                    OwW[l31 * 68 + d] = oacc[dt][reg] * inv;
                }
            asm volatile("s_waitcnt lgkmcnt(0)" ::: "memory");
            const int qq = lane >> 1, half = lane & 1;
            const float* src = &OwW[qq * 68 + half * 32];
            float* dstp = &out[((size_t)b * S_ + q0w + qq) * D_ + h * DH_ + half * 32];
#pragma unroll
            for (int j = 0; j < 8; ++j)
                *(float4*)&dstp[j * 4] = *(const float4*)&src[j * 4];
        }
    }
}

// ---------------------------------------------------------------------------
// Global attention phase A: split-K over 64-key chunks.
// ---------------------------------------------------------------------------
__global__ __launch_bounds__(256) void glob_partial(const float* __restrict__ qg,
                                                    const ushort_t* __restrict__ kg,
                                                    const ushort_t* __restrict__ vg,
                                                    const float* __restrict__ am,
                                                    float* __restrict__ pout,
                                                    float* __restrict__ pm,
                                                    float* __restrict__ pl) {
    const int c = blockIdx.x, h = blockIdx.y, b = blockIdx.z;
    const int t = threadIdx.x;
    const int bh = b * H_ + h;
    const size_t base = (size_t)bh * S_ * DH_;
    const int jg0 = c * CK_;

    __shared__ float qs[G_][DH_];
    __shared__ float kt[CK_][69];
    __shared__ float vt[CK_][68];
    __shared__ float ps[G_][CK_];

    for (int i = t; i < G_ * DH_; i += 256)
        qs[i >> 6][i & 63] = qg[(size_t)(b * G_ + (i >> 6)) * D_ + h * DH_ + (i & 63)];
    {
        const int row = t >> 2, off = (t & 3) * 16;
        const ushort_t* kr = &kg[base + (size_t)(jg0 + row) * DH_ + off];
        const ushort_t* vr = &vg[base + (size_t)(jg0 + row) * DH_ + off];
        s16x8 ka = *(const s16x8*)kr;
        s16x8 kb2 = *(const s16x8*)(kr + 8);
        s16x8 va = *(const s16x8*)vr;
        s16x8 vb = *(const s16x8*)(vr + 8);
#pragma unroll
        for (int i = 0; i < 8; ++i) {
            kt[row][off + i] = bf2f((ushort_t)ka[i]);
            kt[row][off + 8 + i] = bf2f((ushort_t)kb2[i]);
            vt[row][off + i] = bf2f((ushort_t)va[i]);
            vt[row][off + 8 + i] = bf2f((ushort_t)vb[i]);
        }
    }
    __syncthreads();

    const int g = t >> 5, jl = t & 31;
    float sc0 = 0.f, sc1 = 0.f;
#pragma unroll 8
    for (int d = 0; d < DH_; ++d) {
        const float qv = qs[g][d];
        sc0 += qv * kt[jl][d];
        sc1 += qv * kt[jl + 32][d];
    }
    if (!(am[(size_t)b * S_ + jg0 + jl] > 0.5f)) sc0 = NEG_;
    if (!(am[(size_t)b * S_ + jg0 + jl + 32] > 0.5f)) sc1 = NEG_;

    float mm = fmaxf(sc0, sc1);
    mm = fmaxf(mm, __shfl_xor(mm, 1));
    mm = fmaxf(mm, __shfl_xor(mm, 2));
    mm = fmaxf(mm, __shfl_xor(mm, 4));
    mm = fmaxf(mm, __shfl_xor(mm, 8));
    mm = fmaxf(mm, __shfl_xor(mm, 16));
    const float p0 = __expf(sc0 - mm);
    const float p1 = __expf(sc1 - mm);
    float ls = p0 + p1;
    ls += __shfl_xor(ls, 1);
    ls += __shfl_xor(ls, 2);
    ls += __shfl_xor(ls, 4);
    ls += __shfl_xor(ls, 8);
    ls += __shfl_xor(ls, 16);
    ps[g][jl] = p0;
    ps[g][jl + 32] = p1;
    if (jl == 0) {
        pm[((size_t)bh * NC_ + c) * G_ + g] = mm;
        pl[((size_t)bh * NC_ + c) * G_ + g] = ls;
    }
    __syncthreads();

#pragma unroll
    for (int pass = 0; pass < 2; ++pass) {
        const int gg = (t >> 6) + pass * 4;
        const int d = t & 63;
        float acc = 0.f;
#pragma unroll 8
        for (int j = 0; j < CK_; ++j) acc += ps[gg][j] * vt[j][d];
        pout[(((size_t)bh * NC_ + c) * G_ + gg) * DH_ + d] = acc;
    }
}

// ---------------------------------------------------------------------------
// Global attention phase B: combine chunks.
// ---------------------------------------------------------------------------
__global__ __launch_bounds__(256) void glob_reduce(const float* __restrict__ pout,
                                                   const float* __restrict__ pm,
                                                   const float* __restrict__ pl,
                                                   float* __restrict__ out) {
    const int bh = blockIdx.x;
    const int b = bh / H_, h = bh - b * H_;
    const int t = threadIdx.x;

    __shared__ float wc[G_][NC_];
    __shared__ float wsum[G_];

    const int g = t >> 5, cl = t & 31;
    const float m0 = pm[((size_t)bh * NC_ + cl) * G_ + g];
    const float m1 = pm[((size_t)bh * NC_ + cl + 32) * G_ + g];
    float M = fmaxf(m0, m1);
    M = fmaxf(M, __shfl_xor(M, 1));
    M = fmaxf(M, __shfl_xor(M, 2));
    M = fmaxf(M, __shfl_xor(M, 4));
    M = fmaxf(M, __shfl_xor(M, 8));
    M = fmaxf(M, __shfl_xor(M, 16));
    const float w0 = __expf(m0 - M);
    const float w1 = __expf(m1 - M);
    float S = w0 * pl[((size_t)bh * NC_ + cl) * G_ + g] +
              w1 * pl[((size_t)bh * NC_ + cl + 32) * G_ + g];
    S += __shfl_xor(S, 1);
    S += __shfl_xor(S, 2);
    S += __shfl_xor(S, 4);
    S += __shfl_xor(S, 8);
    S += __shfl_xor(S, 16);
    wc[g][cl] = w0;
    wc[g][cl + 32] = w1;
    if (cl == 0) wsum[g] = S;
    __syncthreads();

#pragma unroll
    for (int pass = 0; pass < 2; ++pass) {
        const int gg = (t >> 6) + pass * 4;
        const int d = t & 63;
        float acc = 0.f;
        for (int c2 = 0; c2 < NC_; ++c2)
            acc += wc[gg][c2] * pout[(((size_t)bh * NC_ + c2) * G_ + gg) * DH_ + d];
        out[((size_t)b * S_ + gg) * D_ + h * DH_ + d] = acc / wsum[gg];
    }
}

// ---------------------------------------------------------------------------
extern "C" void kernel_launch(void* const* d_in, const int* in_sizes, int n_in,
                              void* d_out, int out_size, void* d_ws, size_t ws_size,
                              hipStream_t stream) {
    (void)in_sizes; (void)n_in; (void)out_size; (void)ws_size;

    const float* hs    = (const float*)d_in[0];
    const float* amask = (const float*)d_in[1];
    const float* Wq    = (const float*)d_in[2];
    const float* Wk    = (const float*)d_in[3];
    const float* Wv    = (const float*)d_in[4];
    const float* Wqg   = (const float*)d_in[5];
    const float* Wkg   = (const float*)d_in[6];
    const float* Wvg   = (const float*)d_in[7];
    float* out = (float*)d_out;

    char* p = (char*)d_ws;
    ushort_t* hs_bf = (ushort_t*)p; p += (size_t)B_ * S_ * D_ * 2;
    ushort_t* wt    = (ushort_t*)p; p += (size_t)5 * D_ * D_ * 2;
    const size_t per = (size_t)B_ * H_ * S_ * DH_;
    ushort_t* qb  = (ushort_t*)p; p += per * 2;
    ushort_t* kb  = (ushort_t*)p; p += per * 2;
    ushort_t* vb  = (ushort_t*)p; p += per * 2;
    ushort_t* kgb = (ushort_t*)p; p += per * 2;
    ushort_t* vgb = (ushort_t*)p; p += per * 2;
    float* qg   = (float*)p; p += (size_t)B_ * G_ * D_ * 4;
    float* pout = (float*)p; p += (size_t)B_ * H_ * NC_ * G_ * DH_ * 4;
    float* pm   = (float*)p; p += (size_t)B_ * H_ * NC_ * G_ * 4;
    float* pl   = (float*)p;

    convert_hs<<<(B_ * S_ * D_ / 8 + 255) / 256, 256, 0, stream>>>(hs, hs_bf, B_ * S_ * D_ / 8);
    convert_wt<<<dim3(D_ / 32, D_ / 32, 5), 256, 0, stream>>>(Wq, Wk, Wv, Wkg, Wvg, wt);
    proj_mfma<<<dim3(B_ * S_ / 128, 5 * D_ / 128), 256, 0, stream>>>(hs_bf, wt, qb, kb, vb, kgb, vgb);
    qg_gemm<<<dim3(B_ * G_ / 2, D_ / 128), 256, 0, stream>>>(hs, Wqg, qg);
    win_mfma<<<dim3(S_ / W_, H_, B_), 512, 0, stream>>>(qb, kb, vb, amask, out);
    glob_partial<<<dim3(NC_, H_, B_), 256, 0, stream>>>(qg, kgb, vgb, amask, pout, pm, pl);
    glob_reduce<<<B_ * H_, 256, 0, stream>>>(pout, pm, pl, out);
}

// Round 5
// 154.298 us; speedup vs baseline: 10.2039x; 1.3501x over previous
//
#include <hip/hip_runtime.h>

#define B_ 2
#define S_ 4096
#define D_ 768
#define H_ 12
#define DH_ 64
#define W_ 256
#define G_ 8
#define NEG_ (-1e9f)
#define NC_ 64
#define CK_ 64
#define WQB 128
#define NT_ 11

typedef __attribute__((ext_vector_type(4))) float f32x4;
typedef __attribute__((ext_vector_type(16))) float f32x16;
typedef __attribute__((ext_vector_type(8))) short s16x8;
typedef __attribute__((ext_vector_type(4))) short s16x4;
typedef unsigned short ushort_t;

__device__ __forceinline__ unsigned short f2bf(float f) {
    union { float f; unsigned u; } v; v.f = f;
    unsigned r = v.u + 0x7FFFu + ((v.u >> 16) & 1u);
    return (unsigned short)(r >> 16);
}
__device__ __forceinline__ float bf2f(unsigned short b) {
    union { unsigned u; float f; } v; v.u = ((unsigned)b) << 16;
    return v.f;
}
__device__ __forceinline__ unsigned cvtpk_bf16(float lo, float hi) {
    unsigned r;
    asm("v_cvt_pk_bf16_f32 %0, %1, %2" : "=v"(r) : "v"(lo), "v"(hi));
    return r;
}
__device__ __forceinline__ void gload16(const ushort_t* g, ushort_t* l) {
    __builtin_amdgcn_global_load_lds(
        (const __attribute__((address_space(1))) unsigned*)g,
        (__attribute__((address_space(3))) unsigned*)l, 16, 0, 0);
}

// ---------------------------------------------------------------------------
// hs fp32 -> bf16
// ---------------------------------------------------------------------------
__global__ __launch_bounds__(256) void convert_hs(const float* __restrict__ x,
                                                  ushort_t* __restrict__ y, int n8) {
    int i = blockIdx.x * 256 + threadIdx.x;
    if (i >= n8) return;
    float4 a = *(const float4*)&x[(size_t)i * 8];
    float4 c = *(const float4*)&x[(size_t)i * 8 + 4];
    s16x8 o;
    o[0] = (short)f2bf(a.x); o[1] = (short)f2bf(a.y);
    o[2] = (short)f2bf(a.z); o[3] = (short)f2bf(a.w);
    o[4] = (short)f2bf(c.x); o[5] = (short)f2bf(c.y);
    o[6] = (short)f2bf(c.z); o[7] = (short)f2bf(c.w);
    *(s16x8*)&y[(size_t)i * 8] = o;
}

// ---------------------------------------------------------------------------
// Weights: transpose+convert into Wt[w*768 + n][k] (bf16), 0.125 into Wq.
// ---------------------------------------------------------------------------
__global__ __launch_bounds__(256) void convert_wt(const float* __restrict__ W0,
                                                  const float* __restrict__ W1,
                                                  const float* __restrict__ W2,
                                                  const float* __restrict__ W3,
                                                  const float* __restrict__ W4,
                                                  ushort_t* __restrict__ wt) {
    __shared__ float tile[32][33];
    const int w = blockIdx.z;
    const float* Wsrc = (w == 0) ? W0 : (w == 1) ? W1 : (w == 2) ? W2 : (w == 3) ? W3 : W4;
    const float scl = (w == 0) ? 0.125f : 1.0f;
    const int k0 = blockIdx.x * 32;
    const int n0 = blockIdx.y * 32;
    const int t = threadIdx.x;
    const int r = t >> 3, c4 = (t & 7) * 4;
    float4 src = *(const float4*)&Wsrc[(size_t)(k0 + r) * D_ + n0 + c4];
    tile[r][c4 + 0] = src.x; tile[r][c4 + 1] = src.y;
    tile[r][c4 + 2] = src.z; tile[r][c4 + 3] = src.w;
    __syncthreads();
    s16x4 o;
    o[0] = (short)f2bf(tile[c4 + 0][r] * scl);
    o[1] = (short)f2bf(tile[c4 + 1][r] * scl);
    o[2] = (short)f2bf(tile[c4 + 2][r] * scl);
    o[3] = (short)f2bf(tile[c4 + 3][r] * scl);
    *(s16x4*)&wt[((size_t)(w * D_ + n0 + r)) * D_ + k0 + c4] = o;
}

// ---------------------------------------------------------------------------
// Fused projection GEMM, m97-style: BK=64, global_load_lds(16B) with
// pre-swizzled source, XOR-swizzled ds_read_b128, coalesced LDS-transpose
// epilogue.  128x128 tile, 4 waves (2x2).
// ---------------------------------------------------------------------------
__global__ __launch_bounds__(256, 2) void proj_mfma(const ushort_t* __restrict__ A,
                                                    const ushort_t* __restrict__ Bt,
                                                    ushort_t* __restrict__ oq,
                                                    ushort_t* __restrict__ ok,
                                                    ushort_t* __restrict__ ov,
                                                    ushort_t* __restrict__ okg,
                                                    ushort_t* __restrict__ ovg) {
    __shared__ char smem[34048];
    ushort_t* Al = (ushort_t*)smem;            // [128][64] linear, swizzled data
    ushort_t* Bl = Al + 128 * 64;

    const int t = threadIdx.x;
    const int m0 = blockIdx.x * 128;
    const int n0 = blockIdx.y * 128;
    const int lane = t & 63;
    const int w = t >> 6;
    const int wm = (w >> 1) * 64, wn = (w & 1) * 64;
    const int ln = lane & 15, hi = lane >> 4;

    // staging geometry: wave w, call j stages rows (w*4+j)*8 .. +8 (1 KB)
    const int srow_in_call = lane >> 3;                  // 0..7
    const int scol = ((lane & 7) ^ srow_in_call) * 8;    // swizzled source col (u16)

    f32x4 acc[4][4];
#pragma unroll
    for (int mi = 0; mi < 4; ++mi)
#pragma unroll
        for (int ni = 0; ni < 4; ++ni) acc[mi][ni] = (f32x4){0.f, 0.f, 0.f, 0.f};

    for (int k0 = 0; k0 < D_; k0 += 64) {
        __syncthreads();
#pragma unroll
        for (int j = 0; j < 4; ++j) {
            const int rbase = (w * 4 + j) * 8;
            const int row = rbase + srow_in_call;
            gload16(&A[(size_t)(m0 + row) * D_ + k0 + scol], &Al[rbase * 64]);
            gload16(&Bt[(size_t)(n0 + row) * D_ + k0 + scol], &Bl[rbase * 64]);
        }
        __syncthreads();   // compiler inserts vmcnt(0) drain here

#pragma unroll
        for (int ks = 0; ks < 2; ++ks) {
            s16x8 af[4], bf[4];
#pragma unroll
            for (int i = 0; i < 4; ++i) {
                const int ar = wm + i * 16 + ln;
                const int br = wn + i * 16 + ln;
                const int slot = (4 * ks + hi) ^ (ln & 7);
                af[i] = *(const s16x8*)&Al[ar * 64 + slot * 8];
                bf[i] = *(const s16x8*)&Bl[br * 64 + slot * 8];
            }
#pragma unroll
            for (int mi = 0; mi < 4; ++mi)
#pragma unroll
                for (int ni = 0; ni < 4; ++ni)
                    acc[mi][ni] = __builtin_amdgcn_mfma_f32_16x16x32_bf16(af[mi], bf[ni], acc[mi][ni], 0, 0, 0);
        }
    }

    // ---- coalesced epilogue: acc -> f32 LDS [64][132] -> bf16 b128 stores ----
    float* scr = (float*)smem;
    const int rl = t >> 2, cs = (t & 3) * 32;
    const int ng = n0 + cs;
    const int w_idx = ng / D_;
    const int cb = ng - w_idx * D_;
    const int hh = cb >> 6, dd = cb & 63;
    ushort_t* dst = (w_idx == 0) ? oq : (w_idx == 1) ? ok : (w_idx == 2) ? ov
                    : (w_idx == 3) ? okg : ovg;

#pragma unroll
    for (int r = 0; r < 2; ++r) {
        __syncthreads();
        if ((w >> 1) == r) {
#pragma unroll
            for (int mi = 0; mi < 4; ++mi)
#pragma unroll
                for (int ni = 0; ni < 4; ++ni)
#pragma unroll
                    for (int rr = 0; rr < 4; ++rr)
                        scr[(mi * 16 + hi * 4 + rr) * 132 + wn + ni * 16 + ln] = acc[mi][ni][rr];
        }
        __syncthreads();
        const int m = m0 + r * 64 + rl;
        const int bb = m >> 12, s = m & 4095;
        ushort_t* drow = dst + ((size_t)(bb * H_ + hh) * S_ + s) * DH_ + dd;
        const float* srcp = scr + rl * 132 + cs;
#pragma unroll
        for (int seg = 0; seg < 4; ++seg) {
            float4 lo = *(const float4*)&srcp[seg * 8];
            float4 hi4 = *(const float4*)&srcp[seg * 8 + 4];
            s16x8 o;
            o[0] = (short)f2bf(lo.x); o[1] = (short)f2bf(lo.y);
            o[2] = (short)f2bf(lo.z); o[3] = (short)f2bf(lo.w);
            o[4] = (short)f2bf(hi4.x); o[5] = (short)f2bf(hi4.y);
            o[6] = (short)f2bf(hi4.z); o[7] = (short)f2bf(hi4.w);
            *(s16x8*)&drow[seg * 8] = o;
        }
    }
}

// ---------------------------------------------------------------------------
// qg GEMM (tiny).
// ---------------------------------------------------------------------------
__global__ __launch_bounds__(256) void qg_gemm(const float* __restrict__ X,
                                               const float* __restrict__ Wm,
                                               float* __restrict__ qg) {
    const int rp = blockIdx.x;
    const int c0 = blockIdx.y * 128;
    const int t = threadIdx.x;
    const int r = t >> 7, cl = t & 127;
    __shared__ float xr[2][D_];
    for (int i = t; i < 2 * D_; i += 256) {
        const int rr = i / D_, kk = i - rr * D_;
        const int row = rp * 2 + rr;
        const int b = row >> 3, g = row & 7;
        xr[rr][kk] = X[((size_t)b * S_ + g) * D_ + kk];
    }
    __syncthreads();
    float a0 = 0.f, a1 = 0.f, a2 = 0.f, a3 = 0.f;
    const float* wp = &Wm[c0 + cl];
    for (int kk = 0; kk < D_; kk += 4) {
        a0 += xr[r][kk + 0] * wp[(size_t)(kk + 0) * D_];
        a1 += xr[r][kk + 1] * wp[(size_t)(kk + 1) * D_];
        a2 += xr[r][kk + 2] * wp[(size_t)(kk + 2) * D_];
        a3 += xr[r][kk + 3] * wp[(size_t)(kk + 3) * D_];
    }
    const int row = rp * 2 + r;
    qg[(size_t)row * D_ + c0 + cl] = (a0 + a1 + a2 + a3) * 0.125f;
}

// ---------------------------------------------------------------------------
// Windowed attention: 4 waves x 32 queries (128 q/block, 768 blocks),
// 32x32x16 MFMA swapped operands; V^T LDS stride 66 (odd dword) ->
// conflict-free b32 frag reads + ~2-way scatter stores; fast-path interior
// tiles; defer-max rescale (THR=8).
// ---------------------------------------------------------------------------
__global__ __launch_bounds__(256, 2) void win_mfma(const ushort_t* __restrict__ q,
                                                   const ushort_t* __restrict__ k,
                                                   const ushort_t* __restrict__ v,
                                                   const float* __restrict__ am,
                                                   float* __restrict__ out) {
    __shared__ char smem[34816];
    ushort_t* Kl = (ushort_t*)smem;            // [64][72]
    ushort_t* Vt = Kl + 64 * 72;               // [64 d][66 keys]
    unsigned* Mv = (unsigned*)(Vt + 64 * 66);
    float* Ow = (float*)smem;                  // epilogue: [4 waves][32][68]

    const int n = blockIdx.x, h = blockIdx.y, b = blockIdx.z;
    const int t = threadIdx.x;
    const int lane = t & 63, w = t >> 6;
    const int l31 = lane & 31, h5 = lane >> 5;
    const int q0w = n * WQB + w * 32;
    const int q_abs = q0w + l31;
    const size_t bh = (size_t)(b * H_ + h) * S_;

    s16x8 qf[4];
#pragma unroll
    for (int ks = 0; ks < 4; ++ks)
        qf[ks] = *(const s16x8*)&q[(bh + q_abs) * DH_ + ks * 16 + 8 * h5];

    f32x16 oacc[2];
#pragma unroll
    for (int dt = 0; dt < 2; ++dt)
#pragma unroll
        for (int i = 0; i < 16; ++i) oacc[dt][i] = 0.f;
    float m_run = -1e30f, l_run = 0.f;

    const int srow = t >> 2, soff = (t & 3) * 16;

    for (int tt = 0; tt < NT_; ++tt) {
        const bool isg = (tt == 0);
        const int pbase = n * WQB - W_ + (tt - 1) * 64;
        __syncthreads();
        // ---- stage K row-major (b128) + V^T stride-66 scatter ----
        {
            const int p = isg ? srow : pbase + srow;
            const int pr = p < 0 ? 0 : (p >= S_ ? S_ - 1 : p);
            const ushort_t* krow = &k[(bh + pr) * DH_ + soff];
            s16x8 k0v = *(const s16x8*)krow;
            s16x8 k1v = *(const s16x8*)(krow + 8);
            *(s16x8*)&Kl[srow * 72 + soff] = k0v;
            *(s16x8*)&Kl[srow * 72 + soff + 8] = k1v;
            const ushort_t* vrow = &v[(bh + pr) * DH_ + soff];
            s16x8 v0v = *(const s16x8*)vrow;
            s16x8 v1v = *(const s16x8*)(vrow + 8);
#pragma unroll
            for (int i = 0; i < 8; ++i) {
                Vt[(soff + i) * 66 + srow] = (ushort_t)v0v[i];
                Vt[(soff + 8 + i) * 66 + srow] = (ushort_t)v1v[i];
            }
        }
        if (w == 0) {
            const int p2 = isg ? lane : pbase + lane;
            const bool ok = isg ? (lane < G_)
                                : (p2 >= G_ && p2 < S_ && am[(size_t)b * S_ + p2] > 0.5f);
            unsigned long long bal = __ballot(ok);
            if (lane == 0) { Mv[0] = (unsigned)bal; Mv[1] = (unsigned)(bal >> 32); }
        }
        __syncthreads();

        // wave-level band skip
        if (!isg && (pbase > q0w + 31 + W_ || pbase + 63 < q0w - W_)) continue;

        // ---- QK^T (swapped) ----
        f32x16 sc[2];
#pragma unroll
        for (int st = 0; st < 2; ++st)
#pragma unroll
            for (int i = 0; i < 16; ++i) sc[st][i] = 0.f;
#pragma unroll
        for (int st = 0; st < 2; ++st)
#pragma unroll
            for (int ks = 0; ks < 4; ++ks) {
                s16x8 kf = *(const s16x8*)&Kl[(st * 32 + l31) * 72 + ks * 16 + 8 * h5];
                sc[st] = __builtin_amdgcn_mfma_f32_32x32x16_bf16(kf, qf[ks], sc[st], 0, 0, 0);
            }

        // ---- mask (fast-path for interior tiles) ----
        const unsigned mv0 = Mv[0], mv1 = Mv[1];
        const bool fullt = !isg && ((mv0 & mv1) == 0xFFFFFFFFu) &&
                           (pbase >= q0w + 31 - W_) && (pbase + 63 <= q0w + W_);
        float tmax = -1e30f;
        if (fullt) {
#pragma unroll
            for (int st = 0; st < 2; ++st)
#pragma unroll
                for (int reg = 0; reg < 16; ++reg) tmax = fmaxf(tmax, sc[st][reg]);
        } else {
#pragma unroll
            for (int st = 0; st < 2; ++st)
#pragma unroll
                for (int reg = 0; reg < 16; ++reg) {
                    const int cst = (reg & 3) + 8 * (reg >> 2);
                    bool valid;
                    if (isg) {
                        valid = (st == 0) && (cst < 8);
                    } else {
                        const int crow = cst + 4 * h5;
                        const int key_abs = pbase + st * 32 + crow;
                        const unsigned mvx = (st == 0) ? mv0 : mv1;
                        valid = ((mvx >> crow) & 1u) &&
                                (key_abs >= q_abs - W_) && (key_abs <= q_abs + W_);
                    }
                    const float s = valid ? sc[st][reg] : -1e30f;
                    sc[st][reg] = s;
                    tmax = fmaxf(tmax, s);
                }
        }
        tmax = fmaxf(tmax, __shfl_xor(tmax, 32));

        // ---- defer-max online softmax ----
        if (__any(tmax > m_run + 8.f)) {
            const float mnew = fmaxf(m_run, tmax);
            const float f = __expf(m_run - mnew);
            l_run *= f;
#pragma unroll
            for (int dt = 0; dt < 2; ++dt)
#pragma unroll
                for (int i = 0; i < 16; ++i) oacc[dt][i] *= f;
            m_run = mnew;
        }
        float psum = 0.f;
#pragma unroll
        for (int st = 0; st < 2; ++st)
#pragma unroll
            for (int reg = 0; reg < 16; ++reg) {
                const float p = __expf(sc[st][reg] - m_run);
                sc[st][reg] = p;
                psum += p;
            }
        psum += __shfl_xor(psum, 32);
        l_run += psum;

        // ---- P -> bf16 B-fragments (cvt_pk + partner exchange) + PV ----
#pragma unroll
        for (int ks = 0; ks < 4; ++ks) {
            const int st = ks >> 1, k8 = (ks & 1) * 8;
            const unsigned Au = cvtpk_bf16(sc[st][k8 + 0], sc[st][k8 + 1]);
            const unsigned Bu = cvtpk_bf16(sc[st][k8 + 2], sc[st][k8 + 3]);
            const unsigned Cu = cvtpk_bf16(sc[st][k8 + 4], sc[st][k8 + 5]);
            const unsigned Du = cvtpk_bf16(sc[st][k8 + 6], sc[st][k8 + 7]);
            const unsigned send0 = h5 ? Au : Cu;
            const unsigned send1 = h5 ? Bu : Du;
            const unsigned recv0 = __shfl_xor((int)send0, 32);
            const unsigned recv1 = __shfl_xor((int)send1, 32);
            union { unsigned u[4]; s16x8 v8; } pu;
            pu.u[0] = h5 ? recv0 : Au;
            pu.u[1] = h5 ? recv1 : Bu;
            pu.u[2] = h5 ? Cu : recv0;
            pu.u[3] = h5 ? Du : recv1;
#pragma unroll
            for (int dt = 0; dt < 2; ++dt) {
                const int vbase = (dt * 32 + l31) * 66 + ks * 16 + 8 * h5;
                union { unsigned u[4]; s16x8 v8; } vf;
                vf.u[0] = *(const unsigned*)&Vt[vbase + 0];
                vf.u[1] = *(const unsigned*)&Vt[vbase + 2];
                vf.u[2] = *(const unsigned*)&Vt[vbase + 4];
                vf.u[3] = *(const unsigned*)&Vt[vbase + 6];
                oacc[dt] = __builtin_amdgcn_mfma_f32_32x32x16_bf16(vf.v8, pu.v8, oacc[dt], 0, 0, 0);
            }
        }
    }

    // ---- epilogue: O^T -> O via LDS, coalesced store ----
    __syncthreads();
    const float inv = 1.0f / l_run;
    float* OwW = Ow + w * 32 * 68;
#pragma unroll
    for (int dt = 0; dt < 2; ++dt)
#pragma unroll
        for (int reg = 0; reg < 16; ++reg) {
            const int d = dt * 32 + (reg & 3) + 8 * (reg >> 2) + 4 * h5;
            OwW[l31 * 68 + d] = oacc[dt][reg] * inv;
        }
    asm volatile("s_waitcnt lgkmcnt(0)" ::: "memory");
    const int qq = lane >> 1, half = lane & 1;
    const float* src = &OwW[qq * 68 + half * 32];
    float* dstp = &out[((size_t)b * S_ + q0w + qq) * D_ + h * DH_ + half * 32];
#pragma unroll
    for (int j = 0; j < 8; ++j)
        *(float4*)&dstp[j * 4] = *(const float4*)&src[j * 4];
}

// ---------------------------------------------------------------------------
// Global attention phase A: split-K over 64-key chunks.
// ---------------------------------------------------------------------------
__global__ __launch_bounds__(256) void glob_partial(const float* __restrict__ qg,
                                                    const ushort_t* __restrict__ kg,
                                                    const ushort_t* __restrict__ vg,
                                                    const float* __restrict__ am,
                                                    float* __restrict__ pout,
                                                    float* __restrict__ pm,
                                                    float* __restrict__ pl) {
    const int c = blockIdx.x, h = blockIdx.y, b = blockIdx.z;
    const int t = threadIdx.x;
    const int bh = b * H_ + h;
    const size_t base = (size_t)bh * S_ * DH_;
    const int jg0 = c * CK_;

    __shared__ float qs[G_][DH_];
    __shared__ float kt[CK_][69];
    __shared__ float vt[CK_][68];
    __shared__ float ps[G_][CK_];

    for (int i = t; i < G_ * DH_; i += 256)
        qs[i >> 6][i & 63] = qg[(size_t)(b * G_ + (i >> 6)) * D_ + h * DH_ + (i & 63)];
    {
        const int row = t >> 2, off = (t & 3) * 16;
        const ushort_t* kr = &kg[base + (size_t)(jg0 + row) * DH_ + off];
        const ushort_t* vr = &vg[base + (size_t)(jg0 + row) * DH_ + off];
        s16x8 ka = *(const s16x8*)kr;
        s16x8 kb2 = *(const s16x8*)(kr + 8);
        s16x8 va = *(const s16x8*)vr;
        s16x8 vb = *(const s16x8*)(vr + 8);
#pragma unroll
        for (int i = 0; i < 8; ++i) {
            kt[row][off + i] = bf2f((ushort_t)ka[i]);
            kt[row][off + 8 + i] = bf2f((ushort_t)kb2[i]);
            vt[row][off + i] = bf2f((ushort_t)va[i]);
            vt[row][off + 8 + i] = bf2f((ushort_t)vb[i]);
        }
    }
    __syncthreads();

    const int g = t >> 5, jl = t & 31;
    float sc0 = 0.f, sc1 = 0.f;
#pragma unroll 8
    for (int d = 0; d < DH_; ++d) {
        const float qv = qs[g][d];
        sc0 += qv * kt[jl][d];
        sc1 += qv * kt[jl + 32][d];
    }
    if (!(am[(size_t)b * S_ + jg0 + jl] > 0.5f)) sc0 = NEG_;
    if (!(am[(size_t)b * S_ + jg0 + jl + 32] > 0.5f)) sc1 = NEG_;

    float mm = fmaxf(sc0, sc1);
    mm = fmaxf(mm, __shfl_xor(mm, 1));
    mm = fmaxf(mm, __shfl_xor(mm, 2));
    mm = fmaxf(mm, __shfl_xor(mm, 4));
    mm = fmaxf(mm, __shfl_xor(mm, 8));
    mm = fmaxf(mm, __shfl_xor(mm, 16));
    const float p0 = __expf(sc0 - mm);
    const float p1 = __expf(sc1 - mm);
    float ls = p0 + p1;
    ls += __shfl_xor(ls, 1);
    ls += __shfl_xor(ls, 2);
    ls += __shfl_xor(ls, 4);
    ls += __shfl_xor(ls, 8);
    ls += __shfl_xor(ls, 16);
    ps[g][jl] = p0;
    ps[g][jl + 32] = p1;
    if (jl == 0) {
        pm[((size_t)bh * NC_ + c) * G_ + g] = mm;
        pl[((size_t)bh * NC_ + c) * G_ + g] = ls;
    }
    __syncthreads();

#pragma unroll
    for (int pass = 0; pass < 2; ++pass) {
        const int gg = (t >> 6) + pass * 4;
        const int d = t & 63;
        float acc = 0.f;
#pragma unroll 8
        for (int j = 0; j < CK_; ++j) acc += ps[gg][j] * vt[j][d];
        pout[(((size_t)bh * NC_ + c) * G_ + gg) * DH_ + d] = acc;
    }
}

// ---------------------------------------------------------------------------
// Global attention phase B: combine chunks.
// ---------------------------------------------------------------------------
__global__ __launch_bounds__(256) void glob_reduce(const float* __restrict__ pout,
                                                   const float* __restrict__ pm,
                                                   const float* __restrict__ pl,
                                                   float* __restrict__ out) {
    const int bh = blockIdx.x;
    const int b = bh / H_, h = bh - b * H_;
    const int t = threadIdx.x;

    __shared__ float wc[G_][NC_];
    __shared__ float wsum[G_];

    const int g = t >> 5, cl = t & 31;
    const float m0 = pm[((size_t)bh * NC_ + cl) * G_ + g];
    const float m1 = pm[((size_t)bh * NC_ + cl + 32) * G_ + g];
    float M = fmaxf(m0, m1);
    M = fmaxf(M, __shfl_xor(M, 1));
    M = fmaxf(M, __shfl_xor(M, 2));
    M = fmaxf(M, __shfl_xor(M, 4));
    M = fmaxf(M, __shfl_xor(M, 8));
    M = fmaxf(M, __shfl_xor(M, 16));
    const float w0 = __expf(m0 - M);
    const float w1 = __expf(m1 - M);
    float S = w0 * pl[((size_t)bh * NC_ + cl) * G_ + g] +
              w1 * pl[((size_t)bh * NC_ + cl + 32) * G_ + g];
    S += __shfl_xor(S, 1);
    S += __shfl_xor(S, 2);
    S += __shfl_xor(S, 4);
    S += __shfl_xor(S, 8);
    S += __shfl_xor(S, 16);
    wc[g][cl] = w0;
    wc[g][cl + 32] = w1;
    if (cl == 0) wsum[g] = S;
    __syncthreads();

#pragma unroll
    for (int pass = 0; pass < 2; ++pass) {
        const int gg = (t >> 6) + pass * 4;
        const int d = t & 63;
        float acc = 0.f;
        for (int c2 = 0; c2 < NC_; ++c2)
            acc += wc[gg][c2] * pout[(((size_t)bh * NC_ + c2) * G_ + gg) * DH_ + d];
        out[((size_t)b * S_ + gg) * D_ + h * DH_ + d] = acc / wsum[gg];
    }
}

// ---------------------------------------------------------------------------
extern "C" void kernel_launch(void* const* d_in, const int* in_sizes, int n_in,
                              void* d_out, int out_size, void* d_ws, size_t ws_size,
                              hipStream_t stream) {
    (void)in_sizes; (void)n_in; (void)out_size; (void)ws_size;

    const float* hs    = (const float*)d_in[0];
    const float* amask = (const float*)d_in[1];
    const float* Wq    = (const float*)d_in[2];
    const float* Wk    = (const float*)d_in[3];
    const float* Wv    = (const float*)d_in[4];
    const float* Wqg   = (const float*)d_in[5];
    const float* Wkg   = (const float*)d_in[6];
    const float* Wvg   = (const float*)d_in[7];
    float* out = (float*)d_out;

    char* p = (char*)d_ws;
    ushort_t* hs_bf = (ushort_t*)p; p += (size_t)B_ * S_ * D_ * 2;
    ushort_t* wt    = (ushort_t*)p; p += (size_t)5 * D_ * D_ * 2;
    const size_t per = (size_t)B_ * H_ * S_ * DH_;
    ushort_t* qb  = (ushort_t*)p; p += per * 2;
    ushort_t* kb  = (ushort_t*)p; p += per * 2;
    ushort_t* vb  = (ushort_t*)p; p += per * 2;
    ushort_t* kgb = (ushort_t*)p; p += per * 2;
    ushort_t* vgb = (ushort_t*)p; p += per * 2;
    float* qg   = (float*)p; p += (size_t)B_ * G_ * D_ * 4;
    float* pout = (float*)p; p += (size_t)B_ * H_ * NC_ * G_ * DH_ * 4;
    float* pm   = (float*)p; p += (size_t)B_ * H_ * NC_ * G_ * 4;
    float* pl   = (float*)p;

    convert_hs<<<(B_ * S_ * D_ / 8 + 255) / 256, 256, 0, stream>>>(hs, hs_bf, B_ * S_ * D_ / 8);
    convert_wt<<<dim3(D_ / 32, D_ / 32, 5), 256, 0, stream>>>(Wq, Wk, Wv, Wkg, Wvg, wt);
    proj_mfma<<<dim3(B_ * S_ / 128, 5 * D_ / 128), 256, 0, stream>>>(hs_bf, wt, qb, kb, vb, kgb, vgb);
    qg_gemm<<<dim3(B_ * G_ / 2, D_ / 128), 256, 0, stream>>>(hs, Wqg, qg);
    win_mfma<<<dim3(S_ / WQB, H_, B_), 256, 0, stream>>>(qb, kb, vb, amask, out);
    glob_partial<<<dim3(NC_, H_, B_), 256, 0, stream>>>(qg, kgb, vgb, amask, pout, pm, pl);
    glob_reduce<<<B_ * H_, 256, 0, stream>>>(pout, pm, pl, out);
}